// Round 1
// baseline (687.525 us; speedup 1.0000x reference)
//
#include <hip/hip_runtime.h>

// ===== types =====
typedef __attribute__((ext_vector_type(8))) short short8;       // 8 x bf16 bits
typedef __attribute__((ext_vector_type(8))) unsigned short ushort8;
typedef __attribute__((ext_vector_type(4))) float f32x4;
typedef unsigned int uint32;

__device__ __forceinline__ unsigned short f2bf(float f){
  union { float f; unsigned int u; } x; x.f = f;
  unsigned int u = x.u;
  u += 0x7fffu + ((u >> 16) & 1u);   // RNE
  return (unsigned short)(u >> 16);
}
__device__ __forceinline__ uint32 pack2bf(float a, float b){
  return (uint32)f2bf(a) | ((uint32)f2bf(b) << 16);
}

typedef __attribute__((address_space(1))) void gvoid;
typedef __attribute__((address_space(3))) void lvoid;
__device__ __forceinline__ void gload_lds16(const void* g, void* l){
  __builtin_amdgcn_global_load_lds((gvoid*)g, (lvoid*)l, 16, 0, 0);
}

__device__ __forceinline__ f32x4 mfma_bf16(short8 a, short8 b, f32x4 c){
  return __builtin_amdgcn_mfma_f32_16x16x32_bf16(a, b, c, 0, 0, 0);
}

// ===== weight transpose + fp32->bf16: w[K][N] -> wt[N][K] =====
__global__ __launch_bounds__(256) void wtrans_kernel(
    const float* __restrict__ w, unsigned short* __restrict__ wt, int K, int N)
{
  __shared__ float tile[32][33];
  const int n0 = blockIdx.x * 32;
  const int k0 = blockIdx.y * 32;
  const int t = threadIdx.x;
  #pragma unroll
  for (int i = 0; i < 4; i++){
    const int e = t + i * 256;
    const int r = e >> 5, c = e & 31;
    tile[r][c] = w[(size_t)(k0 + r) * N + n0 + c];
  }
  __syncthreads();
  #pragma unroll
  for (int i = 0; i < 4; i++){
    const int e = t + i * 256;
    const int r = e >> 5, c = e & 31;   // r = n-local, c = k-local
    wt[(size_t)(n0 + r) * K + k0 + c] = f2bf(tile[c][r]);
  }
}

// ===== V transpose: qkv[8192][3072] (v at col 2048+h*64) -> vt[bh][64][2048] bf16 =====
__global__ __launch_bounds__(256) void vtrans_kernel(
    const unsigned short* __restrict__ qkv, unsigned short* __restrict__ vt)
{
  __shared__ unsigned short tile[32][33];
  const int bh = blockIdx.z;
  const int b = bh >> 4, h = bh & 15;
  const int t0 = blockIdx.x * 32;
  const int f0 = blockIdx.y * 32;
  const int t = threadIdx.x;
  #pragma unroll
  for (int i = 0; i < 4; i++){
    const int e = t + i * 256;
    const int r = e >> 5, c = e & 31;   // r = t-local, c = feat-local
    tile[r][c] = qkv[(size_t)(b * 2048 + t0 + r) * 3072 + 2048 + h * 64 + f0 + c];
  }
  __syncthreads();
  #pragma unroll
  for (int i = 0; i < 4; i++){
    const int e = t + i * 256;
    const int r = e >> 5, c = e & 31;   // r = feat-local, c = t-local
    vt[((size_t)bh * 64 + f0 + r) * 2048 + t0 + c] = tile[c][r];
  }
}

// ===== LayerNorm fp32 -> bf16 (row = 1024) =====
__global__ __launch_bounds__(256) void ln_kernel(
    const float* __restrict__ x, const float* __restrict__ w, const float* __restrict__ b,
    unsigned short* __restrict__ out)
{
  const int row = blockIdx.x;
  const int t = threadIdx.x;
  const float4 v = ((const float4*)(x + (size_t)row * 1024))[t];
  float s  = v.x + v.y + v.z + v.w;
  float s2 = v.x * v.x + v.y * v.y + v.z * v.z + v.w * v.w;
  #pragma unroll
  for (int off = 32; off > 0; off >>= 1){
    s  += __shfl_xor(s, off);
    s2 += __shfl_xor(s2, off);
  }
  __shared__ float ps[8];
  const int wid = t >> 6;
  if ((t & 63) == 0){ ps[wid] = s; ps[4 + wid] = s2; }
  __syncthreads();
  s  = ps[0] + ps[1] + ps[2] + ps[3];
  s2 = ps[4] + ps[5] + ps[6] + ps[7];
  const float mu  = s * (1.0f / 1024.0f);
  const float var = s2 * (1.0f / 1024.0f) - mu * mu;
  const float rs  = rsqrtf(var + 1e-5f);
  const float4 wv = ((const float4*)w)[t];
  const float4 bv = ((const float4*)b)[t];
  ushort4 ov;
  ov.x = f2bf((v.x - mu) * rs * wv.x + bv.x);
  ov.y = f2bf((v.y - mu) * rs * wv.y + bv.y);
  ov.z = f2bf((v.z - mu) * rs * wv.z + bv.z);
  ov.w = f2bf((v.w - mu) * rs * wv.w + bv.w);
  ((ushort4*)(out + (size_t)row * 1024))[t] = ov;
}

// ===== GEMM: C[M][N] = A[M][K](bf16) * BT[N][K](bf16)^T + bias, epilogues =====
#define EPI_BF16   0
#define EPI_RESF32 1
#define EPI_GELU   2

template<int EPI>
__global__ __launch_bounds__(256) void gemm_kernel(
    const unsigned short* __restrict__ A,
    const unsigned short* __restrict__ BT,
    const float* __restrict__ bias,
    const float* __restrict__ res,
    void* __restrict__ outp,
    int M, int N, int K)
{
  __shared__ unsigned short lA[128 * 32];
  __shared__ unsigned short lB[128 * 32];
  const int tid = threadIdx.x;
  const int lane = tid & 63;
  const int wid = tid >> 6;
  const int wm = wid >> 1;
  const int wn = wid & 1;
  const int m0 = blockIdx.y * 128;
  const int n0 = blockIdx.x * 128;

  const int srow = tid >> 2;
  const int scol = (tid & 3) * 8;
  const unsigned short* gA0 = A  + (size_t)(m0 + srow) * K + scol;
  const unsigned short* gA1 = gA0 + (size_t)64 * K;
  const unsigned short* gB0 = BT + (size_t)(n0 + srow) * K + scol;
  const unsigned short* gB1 = gB0 + (size_t)64 * K;
  unsigned short* dA0 = &lA[tid * 8];
  unsigned short* dA1 = &lA[2048 + tid * 8];
  unsigned short* dB0 = &lB[tid * 8];
  unsigned short* dB1 = &lB[2048 + tid * 8];

  f32x4 acc[4][4];
  #pragma unroll
  for (int i = 0; i < 4; i++)
    #pragma unroll
    for (int j = 0; j < 4; j++) acc[i][j] = (f32x4){0.f, 0.f, 0.f, 0.f};

  const int fr = lane & 15;
  const int fg = lane >> 4;

  for (int kt = 0; kt < K; kt += 32){
    gload_lds16(gA0 + kt, dA0);
    gload_lds16(gA1 + kt, dA1);
    gload_lds16(gB0 + kt, dB0);
    gload_lds16(gB1 + kt, dB1);
    __syncthreads();
    short8 aF[4], bF[4];
    #pragma unroll
    for (int i = 0; i < 4; i++)
      aF[i] = *(const short8*)&lA[(wm * 64 + i * 16 + fr) * 32 + fg * 8];
    #pragma unroll
    for (int j = 0; j < 4; j++)
      bF[j] = *(const short8*)&lB[(wn * 64 + j * 16 + fr) * 32 + fg * 8];
    #pragma unroll
    for (int i = 0; i < 4; i++)
      #pragma unroll
      for (int j = 0; j < 4; j++)
        acc[i][j] = mfma_bf16(aF[i], bF[j], acc[i][j]);
    __syncthreads();
  }

  #pragma unroll
  for (int i = 0; i < 4; i++){
    const int mrow = m0 + wm * 64 + i * 16 + fg * 4;
    #pragma unroll
    for (int j = 0; j < 4; j++){
      const int ncol = n0 + wn * 64 + j * 16 + fr;
      const float bv = bias[ncol];
      #pragma unroll
      for (int r2 = 0; r2 < 4; r2++){
        const size_t idx = (size_t)(mrow + r2) * N + ncol;
        float v = acc[i][j][r2] + bv;
        if (EPI == EPI_RESF32){
          ((float*)outp)[idx] = v + res[idx];
        } else if (EPI == EPI_GELU){
          const float t = tanhf(0.7978845608028654f * (v + 0.044715f * v * v * v));
          ((unsigned short*)outp)[idx] = f2bf(0.5f * v * (1.0f + t));
        } else {
          ((unsigned short*)outp)[idx] = f2bf(v);
        }
      }
    }
  }
}

// ===== causal flash attention: 1 wave per 16 q-rows, KVBLK=32 =====
// S^T = mfma(K, Q): lane -> (kv = 4g+r, q = lane&15). PV: O^T = mfma(VT, P^T).
__global__ __launch_bounds__(64) void attn_kernel(
    const unsigned short* __restrict__ qkv,
    const unsigned short* __restrict__ vt,
    unsigned short* __restrict__ y)
{
  const int bid = blockIdx.x;
  const int bh = bid >> 7;
  const int qt = 127 - (bid & 127);     // big tiles first (causal load balance)
  const int b = bh >> 4, h = bh & 15;
  const int qb = qt * 16;
  const int lane = threadIdx.x;
  const int q16 = lane & 15;
  const int g = lane >> 4;

  __shared__ unsigned short pT[16][40];  // P^T [q][kv 0..31], padded row
  __shared__ float ldsO[16][68];         // O [q][feat 0..63], padded row

  const size_t qrow = ((size_t)(b * 2048 + qb + q16)) * 3072 + h * 64;
  const short8 qf0 = *(const short8*)&qkv[qrow + g * 8];
  const short8 qf1 = *(const short8*)&qkv[qrow + 32 + g * 8];

  const unsigned short* Kb = qkv + (size_t)b * 2048 * 3072 + 1024 + h * 64;
  const unsigned short* Vt = vt + (size_t)bh * 64 * 2048;

  float m = -1e30f, lsum = 0.0f;
  f32x4 o[4];
  #pragma unroll
  for (int i = 0; i < 4; i++) o[i] = (f32x4){0.f, 0.f, 0.f, 0.f};

  const int q_glob = qb + q16;
  const int nkv = (qb + 47) >> 5;

  for (int kb = 0; kb < nkv; kb++){
    const int kvb = kb * 32;
    f32x4 s0 = {0.f, 0.f, 0.f, 0.f}, s1 = {0.f, 0.f, 0.f, 0.f};
    const unsigned short* K0 = Kb + (size_t)(kvb + q16) * 3072;
    const unsigned short* K1 = K0 + 16 * 3072;
    s0 = mfma_bf16(*(const short8*)&K0[g * 8],      qf0, s0);
    s0 = mfma_bf16(*(const short8*)&K0[32 + g * 8], qf1, s0);
    s1 = mfma_bf16(*(const short8*)&K1[g * 8],      qf0, s1);
    s1 = mfma_bf16(*(const short8*)&K1[32 + g * 8], qf1, s1);

    const int kv0 = kvb + 4 * g;
    float p0[4], p1[4];
    float tmax = -1e30f;
    #pragma unroll
    for (int r = 0; r < 4; r++){
      const float v0 = (kv0 + r <= q_glob)      ? s0[r] * 0.125f : -1e30f;
      const float v1 = (kv0 + 16 + r <= q_glob) ? s1[r] * 0.125f : -1e30f;
      p0[r] = v0; p1[r] = v1;
      tmax = fmaxf(tmax, fmaxf(v0, v1));
    }
    tmax = fmaxf(tmax, __shfl_xor(tmax, 16));
    tmax = fmaxf(tmax, __shfl_xor(tmax, 32));
    const float mn = fmaxf(m, tmax);
    const float scale = __expf(m - mn);
    float rowsum = 0.0f;
    #pragma unroll
    for (int r = 0; r < 4; r++){
      p0[r] = __expf(p0[r] - mn);
      p1[r] = __expf(p1[r] - mn);
      rowsum += p0[r] + p1[r];
    }
    rowsum += __shfl_xor(rowsum, 16);
    rowsum += __shfl_xor(rowsum, 32);
    lsum = lsum * scale + rowsum;
    m = mn;
    #pragma unroll
    for (int f = 0; f < 4; f++){
      o[f][0] *= scale; o[f][1] *= scale; o[f][2] *= scale; o[f][3] *= scale;
    }

    __syncthreads();
    *(uint32*)&pT[q16][4 * g]          = pack2bf(p0[0], p0[1]);
    *(uint32*)&pT[q16][4 * g + 2]      = pack2bf(p0[2], p0[3]);
    *(uint32*)&pT[q16][16 + 4 * g]     = pack2bf(p1[0], p1[1]);
    *(uint32*)&pT[q16][16 + 4 * g + 2] = pack2bf(p1[2], p1[3]);
    __syncthreads();
    const short8 pf = *(const short8*)&pT[q16][8 * g];
    #pragma unroll
    for (int f = 0; f < 4; f++){
      const short8 vf = *(const short8*)&Vt[(size_t)(f * 16 + q16) * 2048 + kvb + 8 * g];
      o[f] = mfma_bf16(vf, pf, o[f]);
    }
  }

  const float inv = 1.0f / lsum;
  #pragma unroll
  for (int f = 0; f < 4; f++)
    #pragma unroll
    for (int r = 0; r < 4; r++)
      ldsO[q16][f * 16 + 4 * g + r] = o[f][r] * inv;
  __syncthreads();
  const int qr = lane >> 2;
  const int fq = lane & 3;
  ushort8 w0, w1;
  #pragma unroll
  for (int t = 0; t < 8; t++) w0[t] = f2bf(ldsO[qr][fq * 16 + t]);
  #pragma unroll
  for (int t = 0; t < 8; t++) w1[t] = f2bf(ldsO[qr][fq * 16 + 8 + t]);
  unsigned short* yp = y + (size_t)(b * 2048 + qb + qr) * 1024 + h * 64 + fq * 16;
  *(ushort8*)&yp[0] = w0;
  *(ushort8*)&yp[8] = w1;
}

// ===== launch =====
extern "C" void kernel_launch(void* const* d_in, const int* in_sizes, int n_in,
                              void* d_out, int out_size, void* d_ws, size_t ws_size,
                              hipStream_t stream)
{
  const float* x      = (const float*)d_in[0];
  const float* ln1_w  = (const float*)d_in[1];
  const float* ln1_b  = (const float*)d_in[2];
  const float* w_attn = (const float*)d_in[3];
  const float* b_attn = (const float*)d_in[4];
  const float* w_proj = (const float*)d_in[5];
  const float* b_proj = (const float*)d_in[6];
  const float* ln2_w  = (const float*)d_in[7];
  const float* ln2_b  = (const float*)d_in[8];
  const float* w_fc   = (const float*)d_in[9];
  const float* b_fc   = (const float*)d_in[10];
  const float* w_fc2  = (const float*)d_in[11];
  const float* b_fc2  = (const float*)d_in[12];

  // workspace layout (bytes), total 159,383,552 (~152 MB)
  char* ws = (char*)d_ws;
  unsigned short* wbT_attn = (unsigned short*)(ws + 0);          //  6,291,456  [3072][1024]
  unsigned short* wbT_proj = (unsigned short*)(ws + 6291456);    //  2,097,152  [1024][1024]
  unsigned short* wbT_fc   = (unsigned short*)(ws + 8388608);    //  8,388,608  [4096][1024]
  unsigned short* wbT_fc2  = (unsigned short*)(ws + 16777216);   //  8,388,608  [1024][4096]
  unsigned short* h_bf     = (unsigned short*)(ws + 25165824);   // 16,777,216  [8192][1024]
  unsigned short* qkv_bf   = (unsigned short*)(ws + 41943040);   // 50,331,648  [8192][3072]
  unsigned short* vt_bf    = (unsigned short*)(ws + 92274688);   // 16,777,216  [64][64][2048]
  unsigned short* g_bf     = (unsigned short*)(ws + 41943040);   // alias qkv+vt: [8192][4096]
  unsigned short* y_bf     = (unsigned short*)(ws + 109051904);  // 16,777,216  [8192][1024]
  float*          x1       = (float*)(ws + 125829120);           // 33,554,432  [8192][1024]
  float* outf = (float*)d_out;

  // weight transpose + cvt (per-launch; deterministic, ~17us total)
  wtrans_kernel<<<dim3(3072/32, 1024/32), 256, 0, stream>>>(w_attn, wbT_attn, 1024, 3072);
  wtrans_kernel<<<dim3(1024/32, 1024/32), 256, 0, stream>>>(w_proj, wbT_proj, 1024, 1024);
  wtrans_kernel<<<dim3(4096/32, 1024/32), 256, 0, stream>>>(w_fc,   wbT_fc,   1024, 4096);
  wtrans_kernel<<<dim3(1024/32, 4096/32), 256, 0, stream>>>(w_fc2,  wbT_fc2,  4096, 1024);

  // LN1: x -> h_bf
  ln_kernel<<<8192, 256, 0, stream>>>(x, ln1_w, ln1_b, h_bf);
  // qkv = h @ w_attn + b_attn  (bf16 out)
  gemm_kernel<EPI_BF16><<<dim3(3072/128, 8192/128), 256, 0, stream>>>(
      h_bf, wbT_attn, b_attn, nullptr, qkv_bf, 8192, 3072, 1024);
  // V transpose for PV operand
  vtrans_kernel<<<dim3(64, 2, 64), 256, 0, stream>>>(qkv_bf, vt_bf);
  // causal flash attention -> y_bf
  attn_kernel<<<8192, 64, 0, stream>>>(qkv_bf, vt_bf, y_bf);
  // x1 = x + y @ w_proj + b_proj  (f32 out)
  gemm_kernel<EPI_RESF32><<<dim3(1024/128, 8192/128), 256, 0, stream>>>(
      y_bf, wbT_proj, b_proj, x, x1, 8192, 1024, 1024);
  // LN2: x1 -> h_bf (reuse)
  ln_kernel<<<8192, 256, 0, stream>>>(x1, ln2_w, ln2_b, h_bf);
  // g = gelu(h2 @ w_fc + b_fc)  (bf16 out, aliases dead qkv/vt region)
  gemm_kernel<EPI_GELU><<<dim3(4096/128, 8192/128), 256, 0, stream>>>(
      h_bf, wbT_fc, b_fc, nullptr, g_bf, 8192, 4096, 1024);
  // out = x1 + g @ w_fc2 + b_fc2  (f32 out)
  gemm_kernel<EPI_RESF32><<<dim3(1024/128, 8192/128), 256, 0, stream>>>(
      g_bf, wbT_fc2, b_fc2, x1, outf, 8192, 1024, 4096);
}

// Round 2
// 450.287 us; speedup vs baseline: 1.5269x; 1.5269x over previous
//
#include <hip/hip_runtime.h>

// ===== types =====
typedef __attribute__((ext_vector_type(8))) short short8;       // 8 x bf16 bits
typedef __attribute__((ext_vector_type(8))) unsigned short ushort8;
typedef __attribute__((ext_vector_type(4))) float f32x4;
typedef __attribute__((ext_vector_type(16))) float f32x16;
typedef __attribute__((ext_vector_type(2))) unsigned int uint2v;
typedef unsigned int uint32;

__device__ __forceinline__ unsigned short f2bf(float f){
  union { float f; unsigned int u; } x; x.f = f;
  unsigned int u = x.u;
  u += 0x7fffu + ((u >> 16) & 1u);   // RNE
  return (unsigned short)(u >> 16);
}
__device__ __forceinline__ uint32 pack2bf(float a, float b){
  return (uint32)f2bf(a) | ((uint32)f2bf(b) << 16);
}
__device__ __forceinline__ float bf2f(unsigned short s){
  union { float f; unsigned int u; } x; x.u = ((uint32)s) << 16; return x.f;
}

typedef __attribute__((address_space(1))) void gvoid;
typedef __attribute__((address_space(3))) void lvoid;
__device__ __forceinline__ void gload_lds16(const void* g, void* l){
  __builtin_amdgcn_global_load_lds((gvoid*)g, (lvoid*)l, 16, 0, 0);
}

__device__ __forceinline__ f32x4 mfma_bf16(short8 a, short8 b, f32x4 c){
  return __builtin_amdgcn_mfma_f32_16x16x32_bf16(a, b, c, 0, 0, 0);
}
__device__ __forceinline__ f32x16 mfma32(short8 a, short8 b, f32x16 c){
  return __builtin_amdgcn_mfma_f32_32x32x16_bf16(a, b, c, 0, 0, 0);
}

__device__ __forceinline__ uint32 cvtpk_bf(float lo, float hi){
  uint32 r;
  asm("v_cvt_pk_bf16_f32 %0, %1, %2" : "=v"(r) : "v"(lo), "v"(hi));
  return r;
}
__device__ __forceinline__ void plswap(uint32& a, uint32& b){
  auto r = __builtin_amdgcn_permlane32_swap(a, b, false, false);
  a = r[0]; b = r[1];
}

#if __has_builtin(__builtin_amdgcn_exp2f)
__device__ __forceinline__ float exp2g(float x){ return __builtin_amdgcn_exp2f(x); }
#else
__device__ __forceinline__ float exp2g(float x){ return exp2f(x); }
#endif

__device__ __forceinline__ f32x16 zero16(){
  f32x16 z;
  #pragma unroll
  for (int i = 0; i < 16; i++) z[i] = 0.0f;
  return z;
}

// ===== weight transpose + fp32->bf16: w[K][N] -> wt[N][K] =====
__global__ __launch_bounds__(256) void wtrans_kernel(
    const float* __restrict__ w, unsigned short* __restrict__ wt, int K, int N)
{
  __shared__ float tile[32][33];
  const int n0 = blockIdx.x * 32;
  const int k0 = blockIdx.y * 32;
  const int t = threadIdx.x;
  #pragma unroll
  for (int i = 0; i < 4; i++){
    const int e = t + i * 256;
    const int r = e >> 5, c = e & 31;
    tile[r][c] = w[(size_t)(k0 + r) * N + n0 + c];
  }
  __syncthreads();
  #pragma unroll
  for (int i = 0; i < 4; i++){
    const int e = t + i * 256;
    const int r = e >> 5, c = e & 31;   // r = n-local, c = k-local
    wt[(size_t)(n0 + r) * K + k0 + c] = f2bf(tile[c][r]);
  }
}

// ===== V transpose: qkv[8192][3072] (v at col 2048+h*64) -> vt[bh][64][2048] bf16 =====
__global__ __launch_bounds__(256) void vtrans_kernel(
    const unsigned short* __restrict__ qkv, unsigned short* __restrict__ vt)
{
  __shared__ unsigned short tile[32][33];
  const int bh = blockIdx.z;
  const int b = bh >> 4, h = bh & 15;
  const int t0 = blockIdx.x * 32;
  const int f0 = blockIdx.y * 32;
  const int t = threadIdx.x;
  #pragma unroll
  for (int i = 0; i < 4; i++){
    const int e = t + i * 256;
    const int r = e >> 5, c = e & 31;   // r = t-local, c = feat-local
    tile[r][c] = qkv[(size_t)(b * 2048 + t0 + r) * 3072 + 2048 + h * 64 + f0 + c];
  }
  __syncthreads();
  #pragma unroll
  for (int i = 0; i < 4; i++){
    const int e = t + i * 256;
    const int r = e >> 5, c = e & 31;   // r = feat-local, c = t-local
    vt[((size_t)bh * 64 + f0 + r) * 2048 + t0 + c] = tile[c][r];
  }
}

// ===== LayerNorm fp32 -> bf16 (row = 1024) =====
__global__ __launch_bounds__(256) void ln_kernel(
    const float* __restrict__ x, const float* __restrict__ w, const float* __restrict__ b,
    unsigned short* __restrict__ out)
{
  const int row = blockIdx.x;
  const int t = threadIdx.x;
  const float4 v = ((const float4*)(x + (size_t)row * 1024))[t];
  float s  = v.x + v.y + v.z + v.w;
  float s2 = v.x * v.x + v.y * v.y + v.z * v.z + v.w * v.w;
  #pragma unroll
  for (int off = 32; off > 0; off >>= 1){
    s  += __shfl_xor(s, off);
    s2 += __shfl_xor(s2, off);
  }
  __shared__ float ps[8];
  const int wid = t >> 6;
  if ((t & 63) == 0){ ps[wid] = s; ps[4 + wid] = s2; }
  __syncthreads();
  s  = ps[0] + ps[1] + ps[2] + ps[3];
  s2 = ps[4] + ps[5] + ps[6] + ps[7];
  const float mu  = s * (1.0f / 1024.0f);
  const float var = s2 * (1.0f / 1024.0f) - mu * mu;
  const float rs  = rsqrtf(var + 1e-5f);
  const float4 wv = ((const float4*)w)[t];
  const float4 bv = ((const float4*)b)[t];
  ushort4 ov;
  ov.x = f2bf((v.x - mu) * rs * wv.x + bv.x);
  ov.y = f2bf((v.y - mu) * rs * wv.y + bv.y);
  ov.z = f2bf((v.z - mu) * rs * wv.z + bv.z);
  ov.w = f2bf((v.w - mu) * rs * wv.w + bv.w);
  ((ushort4*)(out + (size_t)row * 1024))[t] = ov;
}

// ===== GEMM: C[M][N] = A[M][K](bf16) * BT[N][K](bf16)^T + bias, epilogues =====
#define EPI_BF16   0
#define EPI_RESF32 1
#define EPI_GELU   2

template<int EPI>
__global__ __launch_bounds__(256) void gemm_kernel(
    const unsigned short* __restrict__ A,
    const unsigned short* __restrict__ BT,
    const float* __restrict__ bias,
    const float* __restrict__ res,
    void* __restrict__ outp,
    int M, int N, int K)
{
  __shared__ unsigned short lA[128 * 32];
  __shared__ unsigned short lB[128 * 32];
  const int tid = threadIdx.x;
  const int lane = tid & 63;
  const int wid = tid >> 6;
  const int wm = wid >> 1;
  const int wn = wid & 1;
  const int m0 = blockIdx.y * 128;
  const int n0 = blockIdx.x * 128;

  const int srow = tid >> 2;
  const int scol = (tid & 3) * 8;
  const unsigned short* gA0 = A  + (size_t)(m0 + srow) * K + scol;
  const unsigned short* gA1 = gA0 + (size_t)64 * K;
  const unsigned short* gB0 = BT + (size_t)(n0 + srow) * K + scol;
  const unsigned short* gB1 = gB0 + (size_t)64 * K;
  unsigned short* dA0 = &lA[tid * 8];
  unsigned short* dA1 = &lA[2048 + tid * 8];
  unsigned short* dB0 = &lB[tid * 8];
  unsigned short* dB1 = &lB[2048 + tid * 8];

  f32x4 acc[4][4];
  #pragma unroll
  for (int i = 0; i < 4; i++)
    #pragma unroll
    for (int j = 0; j < 4; j++) acc[i][j] = (f32x4){0.f, 0.f, 0.f, 0.f};

  const int fr = lane & 15;
  const int fg = lane >> 4;

  for (int kt = 0; kt < K; kt += 32){
    gload_lds16(gA0 + kt, dA0);
    gload_lds16(gA1 + kt, dA1);
    gload_lds16(gB0 + kt, dB0);
    gload_lds16(gB1 + kt, dB1);
    __syncthreads();
    short8 aF[4], bF[4];
    #pragma unroll
    for (int i = 0; i < 4; i++)
      aF[i] = *(const short8*)&lA[(wm * 64 + i * 16 + fr) * 32 + fg * 8];
    #pragma unroll
    for (int j = 0; j < 4; j++)
      bF[j] = *(const short8*)&lB[(wn * 64 + j * 16 + fr) * 32 + fg * 8];
    #pragma unroll
    for (int i = 0; i < 4; i++)
      #pragma unroll
      for (int j = 0; j < 4; j++)
        acc[i][j] = mfma_bf16(aF[i], bF[j], acc[i][j]);
    __syncthreads();
  }

  #pragma unroll
  for (int i = 0; i < 4; i++){
    const int mrow = m0 + wm * 64 + i * 16 + fg * 4;
    #pragma unroll
    for (int j = 0; j < 4; j++){
      const int ncol = n0 + wn * 64 + j * 16 + fr;
      const float bv = bias[ncol];
      #pragma unroll
      for (int r2 = 0; r2 < 4; r2++){
        const size_t idx = (size_t)(mrow + r2) * N + ncol;
        float v = acc[i][j][r2] + bv;
        if (EPI == EPI_RESF32){
          ((float*)outp)[idx] = v + res[idx];
        } else if (EPI == EPI_GELU){
          const float t = tanhf(0.7978845608028654f * (v + 0.044715f * v * v * v));
          ((unsigned short*)outp)[idx] = f2bf(0.5f * v * (1.0f + t));
        } else {
          ((unsigned short*)outp)[idx] = f2bf(v);
        }
      }
    }
  }
}

// ===== causal flash attention v2 =====
// Block: 4 waves x 32 q-rows = 128 q rows of one (b,h). KVBLK=64, K/VT LDS
// double-buffered (stage-before-compute, one barrier per tile). Swapped QK^T
// (mfma(K,Q), 32x32x16): lane holds S[kv][q=lane&31], kv=(r&3)+8*(r>>2)+4*hi.
// Softmax in-register (exp2 domain, 0.125*log2e folded into Q), defer-max
// THR=10. P->bf16 via v_cvt_pk + permlane32_swap -> PV B-frags in-register.
// PV: O^T[f][q] = mfma(VT, P^T). LDS XOR-swizzle (16B slot ^= row&7) with
// inverse-swizzled global source (global_load_lds writes linear).

template<bool MASK>
__device__ __forceinline__ void attn_tile(
    const unsigned short* __restrict__ Kc, const unsigned short* __restrict__ Vc,
    const short8 (&qf)[4], int kvbase, int qg, int l31, int hi,
    float& m_r, float& lsum, f32x16& Oa, f32x16& Ob)
{
  f32x16 Sa = zero16();
  f32x16 Sb = zero16();
  const int xb = l31 & 7;
  #pragma unroll
  for (int kk = 0; kk < 4; kk++){
    const int x = kk * 2 + hi;
    const short8 k0 = *(const short8*)((const char*)Kc + l31 * 128 + ((x ^ xb) << 4));
    const short8 k1 = *(const short8*)((const char*)Kc + (l31 + 32) * 128 + ((x ^ xb) << 4));
    Sa = mfma32(k0, qf[kk], Sa);
    Sb = mfma32(k1, qf[kk], Sb);
  }
  if (MASK){
    #pragma unroll
    for (int r = 0; r < 16; r++){
      const int kva = kvbase + (r & 3) + 8 * (r >> 2) + 4 * hi;
      Sa[r] = (kva > qg)      ? -1e30f : Sa[r];
      Sb[r] = (kva + 32 > qg) ? -1e30f : Sb[r];
    }
  }
  float tmax = Sa[0];
  #pragma unroll
  for (int r = 1; r < 16; r++) tmax = fmaxf(tmax, Sa[r]);
  #pragma unroll
  for (int r = 0; r < 16; r++) tmax = fmaxf(tmax, Sb[r]);
  tmax = fmaxf(tmax, __shfl_xor(tmax, 32));
  if (__any(tmax > m_r + 10.0f)){
    const float mn = fmaxf(m_r, tmax);
    const float sc = exp2g(m_r - mn);
    m_r = mn;
    lsum *= sc;
    #pragma unroll
    for (int r = 0; r < 16; r++){ Oa[r] *= sc; Ob[r] *= sc; }
  }
  float rs = 0.0f;
  #pragma unroll
  for (int r = 0; r < 16; r++){
    Sa[r] = exp2g(Sa[r] - m_r); rs += Sa[r];
    Sb[r] = exp2g(Sb[r] - m_r); rs += Sb[r];
  }
  rs += __shfl_xor(rs, 32);
  lsum += rs;

  // P fragments: B[k=kv][n=q], lane holds kv = 8*hi + j (+16*kk)
  short8 pf[4];
  {
    uint32 a0 = cvtpk_bf(Sa[0], Sa[1]),   b0 = cvtpk_bf(Sa[4], Sa[5]);
    uint32 a1 = cvtpk_bf(Sa[2], Sa[3]),   b1 = cvtpk_bf(Sa[6], Sa[7]);
    plswap(a0, b0); plswap(a1, b1);
    uint32 a2 = cvtpk_bf(Sa[8], Sa[9]),   b2 = cvtpk_bf(Sa[12], Sa[13]);
    uint32 a3 = cvtpk_bf(Sa[10], Sa[11]), b3 = cvtpk_bf(Sa[14], Sa[15]);
    plswap(a2, b2); plswap(a3, b3);
    union { uint32 u[4]; short8 s; } m0, m1;
    m0.u[0] = a0; m0.u[1] = a1; m0.u[2] = b0; m0.u[3] = b1;
    m1.u[0] = a2; m1.u[1] = a3; m1.u[2] = b2; m1.u[3] = b3;
    pf[0] = m0.s; pf[1] = m1.s;
  }
  {
    uint32 a0 = cvtpk_bf(Sb[0], Sb[1]),   b0 = cvtpk_bf(Sb[4], Sb[5]);
    uint32 a1 = cvtpk_bf(Sb[2], Sb[3]),   b1 = cvtpk_bf(Sb[6], Sb[7]);
    plswap(a0, b0); plswap(a1, b1);
    uint32 a2 = cvtpk_bf(Sb[8], Sb[9]),   b2 = cvtpk_bf(Sb[12], Sb[13]);
    uint32 a3 = cvtpk_bf(Sb[10], Sb[11]), b3 = cvtpk_bf(Sb[14], Sb[15]);
    plswap(a2, b2); plswap(a3, b3);
    union { uint32 u[4]; short8 s; } m0, m1;
    m0.u[0] = a0; m0.u[1] = a1; m0.u[2] = b0; m0.u[3] = b1;
    m1.u[0] = a2; m1.u[1] = a3; m1.u[2] = b2; m1.u[3] = b3;
    pf[2] = m0.s; pf[3] = m1.s;
  }
  #pragma unroll
  for (int kk = 0; kk < 4; kk++){
    const int x = kk * 2 + hi;
    const short8 v0 = *(const short8*)((const char*)Vc + l31 * 128 + ((x ^ xb) << 4));
    const short8 v1 = *(const short8*)((const char*)Vc + (l31 + 32) * 128 + ((x ^ xb) << 4));
    Oa = mfma32(v0, pf[kk], Oa);
    Ob = mfma32(v1, pf[kk], Ob);
  }
}

__global__ __launch_bounds__(256) void attn_kernel(
    const unsigned short* __restrict__ qkv,
    const unsigned short* __restrict__ vt,
    unsigned short* __restrict__ y)
{
  __shared__ __align__(16) unsigned short Klds[2][4096];
  __shared__ __align__(16) unsigned short Vlds[2][4096];
  const int bid = blockIdx.x;
  const int bh = bid & 63;           // grid = qb_i*64 + bh -> all qb of a bh on one XCD
  const int qb_i = bid >> 6;
  const int b = bh >> 4, h = bh & 15;
  const int qb0 = qb_i * 128;
  const int tid = threadIdx.x;
  const int w = tid >> 6;
  const int lane = tid & 63;
  const int l31 = lane & 31;
  const int hi = lane >> 5;

  // Q frags (B-operand: lane holds Q[q=lane&31][f=16*kk+8*hi+j]), pre-scaled
  // by 0.125*log2(e) so softmax runs in exp2 domain.
  const int qrow_g = b * 2048 + qb0 + w * 32 + l31;
  const unsigned short* qp = qkv + (size_t)qrow_g * 3072 + h * 64;
  short8 qf[4];
  #pragma unroll
  for (int kk = 0; kk < 4; kk++){
    short8 raw = *(const short8*)&qp[kk * 16 + hi * 8];
    #pragma unroll
    for (int j = 0; j < 8; j++)
      qf[kk][j] = (short)f2bf(bf2f((unsigned short)raw[j]) * 0.18033688011112042f);
  }

  // staging geometry: thread -> (row sr / row sr+32, swizzled 16B slot)
  const int sr = tid >> 3;                       // 0..31
  const int ce = ((tid & 7) ^ (sr & 7)) * 8;     // inverse-swizzled source col (elems)
  const unsigned short* kb = qkv + (size_t)(b * 2048) * 3072 + 1024 + h * 64;
  const unsigned short* vb = vt + (size_t)bh * 64 * 2048;

  f32x16 Oa = zero16(), Ob = zero16();
  float m_r = -1e30f, lsum = 0.0f;
  const int qmin = qb0 + w * 32;
  const int qmax = qmin + 31;
  const int qg = qmin + l31;
  const int nkv = (qb0 >> 6) + 2;

#define STAGE(t, bb) do { \
    const size_t kro = (size_t)((t) * 64 + sr) * 3072; \
    gload_lds16(kb + kro + ce,                         (char*)&Klds[bb][0] + tid * 16); \
    gload_lds16(kb + kro + (size_t)32 * 3072 + ce,     (char*)&Klds[bb][0] + 4096 + tid * 16); \
    gload_lds16(vb + (size_t)sr * 2048 + (t) * 64 + ce,        (char*)&Vlds[bb][0] + tid * 16); \
    gload_lds16(vb + (size_t)(sr + 32) * 2048 + (t) * 64 + ce, (char*)&Vlds[bb][0] + 4096 + tid * 16); \
  } while (0)

  STAGE(0, 0);
  __syncthreads();
  int cur = 0;
  for (int kvt = 0; kvt < nkv; kvt++){
    if (kvt + 1 < nkv){
      if (cur) STAGE(kvt + 1, 0); else STAGE(kvt + 1, 1);
    }
    if (kvt * 64 <= qmax){
      if (kvt * 64 + 63 <= qmin)
        attn_tile<false>(Klds[cur], Vlds[cur], qf, kvt * 64, qg, l31, hi, m_r, lsum, Oa, Ob);
      else
        attn_tile<true >(Klds[cur], Vlds[cur], qf, kvt * 64, qg, l31, hi, m_r, lsum, Oa, Ob);
    }
    __syncthreads();
    cur ^= 1;
  }
#undef STAGE

  // epilogue: O^T regs -> y[q][h*64+f]; f = 8*c2 + 4*hi + (0..3) (+32 for Ob)
  const float inv = 1.0f / lsum;
  unsigned short* yp = y + (size_t)qrow_g * 1024 + h * 64;
  #pragma unroll
  for (int c2 = 0; c2 < 4; c2++){
    uint2v da, db;
    da.x = cvtpk_bf(Oa[4 * c2 + 0] * inv, Oa[4 * c2 + 1] * inv);
    da.y = cvtpk_bf(Oa[4 * c2 + 2] * inv, Oa[4 * c2 + 3] * inv);
    *(uint2v*)&yp[8 * c2 + 4 * hi] = da;
    db.x = cvtpk_bf(Ob[4 * c2 + 0] * inv, Ob[4 * c2 + 1] * inv);
    db.y = cvtpk_bf(Ob[4 * c2 + 2] * inv, Ob[4 * c2 + 3] * inv);
    *(uint2v*)&yp[32 + 8 * c2 + 4 * hi] = db;
  }
}

// ===== launch =====
extern "C" void kernel_launch(void* const* d_in, const int* in_sizes, int n_in,
                              void* d_out, int out_size, void* d_ws, size_t ws_size,
                              hipStream_t stream)
{
  const float* x      = (const float*)d_in[0];
  const float* ln1_w  = (const float*)d_in[1];
  const float* ln1_b  = (const float*)d_in[2];
  const float* w_attn = (const float*)d_in[3];
  const float* b_attn = (const float*)d_in[4];
  const float* w_proj = (const float*)d_in[5];
  const float* b_proj = (const float*)d_in[6];
  const float* ln2_w  = (const float*)d_in[7];
  const float* ln2_b  = (const float*)d_in[8];
  const float* w_fc   = (const float*)d_in[9];
  const float* b_fc   = (const float*)d_in[10];
  const float* w_fc2  = (const float*)d_in[11];
  const float* b_fc2  = (const float*)d_in[12];

  // workspace layout (bytes), total 159,383,552 (~152 MB)
  char* ws = (char*)d_ws;
  unsigned short* wbT_attn = (unsigned short*)(ws + 0);          //  [3072][1024]
  unsigned short* wbT_proj = (unsigned short*)(ws + 6291456);    //  [1024][1024]
  unsigned short* wbT_fc   = (unsigned short*)(ws + 8388608);    //  [4096][1024]
  unsigned short* wbT_fc2  = (unsigned short*)(ws + 16777216);   //  [1024][4096]
  unsigned short* h_bf     = (unsigned short*)(ws + 25165824);   //  [8192][1024]
  unsigned short* qkv_bf   = (unsigned short*)(ws + 41943040);   //  [8192][3072]
  unsigned short* vt_bf    = (unsigned short*)(ws + 92274688);   //  [64][64][2048]
  unsigned short* g_bf     = (unsigned short*)(ws + 41943040);   //  alias qkv+vt: [8192][4096]
  unsigned short* y_bf     = (unsigned short*)(ws + 109051904);  //  [8192][1024]
  float*          x1       = (float*)(ws + 125829120);           //  [8192][1024]
  float* outf = (float*)d_out;

  wtrans_kernel<<<dim3(3072/32, 1024/32), 256, 0, stream>>>(w_attn, wbT_attn, 1024, 3072);
  wtrans_kernel<<<dim3(1024/32, 1024/32), 256, 0, stream>>>(w_proj, wbT_proj, 1024, 1024);
  wtrans_kernel<<<dim3(4096/32, 1024/32), 256, 0, stream>>>(w_fc,   wbT_fc,   1024, 4096);
  wtrans_kernel<<<dim3(1024/32, 4096/32), 256, 0, stream>>>(w_fc2,  wbT_fc2,  4096, 1024);

  // LN1: x -> h_bf
  ln_kernel<<<8192, 256, 0, stream>>>(x, ln1_w, ln1_b, h_bf);
  // qkv = h @ w_attn + b_attn  (bf16 out)
  gemm_kernel<EPI_BF16><<<dim3(3072/128, 8192/128), 256, 0, stream>>>(
      h_bf, wbT_attn, b_attn, nullptr, qkv_bf, 8192, 3072, 1024);
  // V transpose for PV operand
  vtrans_kernel<<<dim3(64, 2, 64), 256, 0, stream>>>(qkv_bf, vt_bf);
  // causal flash attention -> y_bf   (grid = qb_i*64 + bh)
  attn_kernel<<<1024, 256, 0, stream>>>(qkv_bf, vt_bf, y_bf);
  // x1 = x + y @ w_proj + b_proj  (f32 out)
  gemm_kernel<EPI_RESF32><<<dim3(1024/128, 8192/128), 256, 0, stream>>>(
      y_bf, wbT_proj, b_proj, x, x1, 8192, 1024, 1024);
  // LN2: x1 -> h_bf (reuse)
  ln_kernel<<<8192, 256, 0, stream>>>(x1, ln2_w, ln2_b, h_bf);
  // g = gelu(h2 @ w_fc + b_fc)  (bf16 out, aliases dead qkv/vt region)
  gemm_kernel<EPI_GELU><<<dim3(4096/128, 8192/128), 256, 0, stream>>>(
      h_bf, wbT_fc, b_fc, nullptr, g_bf, 8192, 4096, 1024);
  // out = x1 + g @ w_fc2 + b_fc2  (f32 out)
  gemm_kernel<EPI_RESF32><<<dim3(1024/128, 8192/128), 256, 0, stream>>>(
      g_bf, wbT_fc2, b_fc2, x1, outf, 8192, 1024, 4096);
}

// Round 3
// 403.462 us; speedup vs baseline: 1.7041x; 1.1161x over previous
//
#include <hip/hip_runtime.h>

// ===== types =====
typedef __attribute__((ext_vector_type(8))) short short8;       // 8 x bf16 bits
typedef __attribute__((ext_vector_type(8))) unsigned short ushort8;
typedef __attribute__((ext_vector_type(4))) float f32x4;
typedef __attribute__((ext_vector_type(16))) float f32x16;
typedef __attribute__((ext_vector_type(2))) unsigned int uint2v;
typedef unsigned int uint32;

__device__ __forceinline__ unsigned short f2bf(float f){
  union { float f; unsigned int u; } x; x.f = f;
  unsigned int u = x.u;
  u += 0x7fffu + ((u >> 16) & 1u);   // RNE
  return (unsigned short)(u >> 16);
}
__device__ __forceinline__ float bf2f(unsigned short s){
  union { float f; unsigned int u; } x; x.u = ((uint32)s) << 16; return x.f;
}

typedef __attribute__((address_space(1))) void gvoid;
typedef __attribute__((address_space(3))) void lvoid;
__device__ __forceinline__ void gload_lds16(const void* g, void* l){
  __builtin_amdgcn_global_load_lds((gvoid*)g, (lvoid*)l, 16, 0, 0);
}

__device__ __forceinline__ f32x4 mfma_bf16(short8 a, short8 b, f32x4 c){
  return __builtin_amdgcn_mfma_f32_16x16x32_bf16(a, b, c, 0, 0, 0);
}
__device__ __forceinline__ f32x16 mfma32(short8 a, short8 b, f32x16 c){
  return __builtin_amdgcn_mfma_f32_32x32x16_bf16(a, b, c, 0, 0, 0);
}

__device__ __forceinline__ uint32 cvtpk_bf(float lo, float hi){
  uint32 r;
  asm("v_cvt_pk_bf16_f32 %0, %1, %2" : "=v"(r) : "v"(lo), "v"(hi));
  return r;
}
__device__ __forceinline__ void plswap(uint32& a, uint32& b){
  auto r = __builtin_amdgcn_permlane32_swap(a, b, false, false);
  a = r[0]; b = r[1];
}

#if __has_builtin(__builtin_amdgcn_exp2f)
__device__ __forceinline__ float exp2g(float x){ return __builtin_amdgcn_exp2f(x); }
#else
__device__ __forceinline__ float exp2g(float x){ return exp2f(x); }
#endif

__device__ __forceinline__ f32x16 zero16(){
  f32x16 z;
  #pragma unroll
  for (int i = 0; i < 16; i++) z[i] = 0.0f;
  return z;
}

// ===== weight transpose + fp32->bf16: w[K][N] -> wt[N][K] =====
__global__ __launch_bounds__(256) void wtrans_kernel(
    const float* __restrict__ w, unsigned short* __restrict__ wt, int K, int N)
{
  __shared__ float tile[32][33];
  const int n0 = blockIdx.x * 32;
  const int k0 = blockIdx.y * 32;
  const int t = threadIdx.x;
  #pragma unroll
  for (int i = 0; i < 4; i++){
    const int e = t + i * 256;
    const int r = e >> 5, c = e & 31;
    tile[r][c] = w[(size_t)(k0 + r) * N + n0 + c];
  }
  __syncthreads();
  #pragma unroll
  for (int i = 0; i < 4; i++){
    const int e = t + i * 256;
    const int r = e >> 5, c = e & 31;   // r = n-local, c = k-local
    wt[(size_t)(n0 + r) * K + k0 + c] = f2bf(tile[c][r]);
  }
}

// ===== V transpose: qkv[8192][3072] (v at col 2048+h*64) -> vt[bh][64][2048] bf16 =====
__global__ __launch_bounds__(256) void vtrans_kernel(
    const unsigned short* __restrict__ qkv, unsigned short* __restrict__ vt)
{
  __shared__ unsigned short tile[32][33];
  const int bh = blockIdx.z;
  const int b = bh >> 4, h = bh & 15;
  const int t0 = blockIdx.x * 32;
  const int f0 = blockIdx.y * 32;
  const int t = threadIdx.x;
  #pragma unroll
  for (int i = 0; i < 4; i++){
    const int e = t + i * 256;
    const int r = e >> 5, c = e & 31;   // r = t-local, c = feat-local
    tile[r][c] = qkv[(size_t)(b * 2048 + t0 + r) * 3072 + 2048 + h * 64 + f0 + c];
  }
  __syncthreads();
  #pragma unroll
  for (int i = 0; i < 4; i++){
    const int e = t + i * 256;
    const int r = e >> 5, c = e & 31;   // r = feat-local, c = t-local
    vt[((size_t)bh * 64 + f0 + r) * 2048 + t0 + c] = tile[c][r];
  }
}

// ===== LayerNorm fp32 -> bf16 (row = 1024) =====
__global__ __launch_bounds__(256) void ln_kernel(
    const float* __restrict__ x, const float* __restrict__ w, const float* __restrict__ b,
    unsigned short* __restrict__ out)
{
  const int row = blockIdx.x;
  const int t = threadIdx.x;
  const float4 v = ((const float4*)(x + (size_t)row * 1024))[t];
  float s  = v.x + v.y + v.z + v.w;
  float s2 = v.x * v.x + v.y * v.y + v.z * v.z + v.w * v.w;
  #pragma unroll
  for (int off = 32; off > 0; off >>= 1){
    s  += __shfl_xor(s, off);
    s2 += __shfl_xor(s2, off);
  }
  __shared__ float ps[8];
  const int wid = t >> 6;
  if ((t & 63) == 0){ ps[wid] = s; ps[4 + wid] = s2; }
  __syncthreads();
  s  = ps[0] + ps[1] + ps[2] + ps[3];
  s2 = ps[4] + ps[5] + ps[6] + ps[7];
  const float mu  = s * (1.0f / 1024.0f);
  const float var = s2 * (1.0f / 1024.0f) - mu * mu;
  const float rs  = rsqrtf(var + 1e-5f);
  const float4 wv = ((const float4*)w)[t];
  const float4 bv = ((const float4*)b)[t];
  ushort4 ov;
  ov.x = f2bf((v.x - mu) * rs * wv.x + bv.x);
  ov.y = f2bf((v.y - mu) * rs * wv.y + bv.y);
  ov.z = f2bf((v.z - mu) * rs * wv.z + bv.z);
  ov.w = f2bf((v.w - mu) * rs * wv.w + bv.w);
  ((ushort4*)(out + (size_t)row * 1024))[t] = ov;
}

// ===== GEMM v2: phase-pipelined ring-3 (T2+T3+T4+T5) ======================
// C[M][N] = A[M][K](bf16) @ BT[N][K]^T + bias (+res / gelu).
// BM=256 BN=128 BK=64, 512 thr = 8 waves (4M x 2N), per-wave 64x64 acc[4][4].
// LDS ring of 3 slots (A 32KB + B 16KB each, 144KB): compute tile t from slot
// t%3 while staging tile t+2 into slot (t+2)%3 via global_load_lds(16B).
// Counted vmcnt(6) once per tile (never 0 in steady state). 2 phases/tile:
// {ds_read frags || stage 3 halves -> barrier -> lgkmcnt(0) -> setprio(1) ->
//  16 MFMA -> setprio(0) -> barrier}. LDS 16B-slot XOR (row&7) swizzle,
// inverse-swizzled global source (both-sides rule).
#define EPI_BF16   0
#define EPI_RESF32 1
#define EPI_GELU   2

template<int EPI>
__global__ __launch_bounds__(512) void gemm2_kernel(
    const unsigned short* __restrict__ A,
    const unsigned short* __restrict__ BT,
    const float* __restrict__ bias,
    const float* __restrict__ res,
    void* __restrict__ outp,
    int M, int N, int K)
{
  __shared__ __align__(16) char lds_all[3 * 49152];

  // XCD-aware bijective swizzle (nwg % 8 == 0 for all our shapes)
  const int nwg = gridDim.x;
  const int bid = blockIdx.x;
  const int wg = (bid & 7) * (nwg >> 3) + (bid >> 3);
  const int NT = N >> 7;
  const int mt = wg / NT;
  const int ntile = wg - mt * NT;
  const int m0 = mt << 8;
  const int n0 = ntile << 7;

  const int tid = threadIdx.x;
  const int lane = tid & 63;
  const int wid = tid >> 6;
  const int wv_m = wid >> 1;      // 0..3 -> 64-row band
  const int wv_n = wid & 1;       // 0..1 -> 64-col band
  const int fr = lane & 15;
  const int fg = lane >> 4;

  // staging geometry: thread -> (row = tid>>3 within 64-row chunk, 16B slot)
  const int srow = tid >> 3;
  const int scol = ((tid & 7) ^ (srow & 7)) << 3;    // inverse-swizzled source col
  const unsigned short* aP = A  + (size_t)(m0 + srow) * K + scol;
  const unsigned short* bP = BT + (size_t)(n0 + srow) * K + scol;
  const size_t rK64 = (size_t)64 * K;

  // LDS read offsets (precomputed, tile-slot-relative)
  int aOff[4][2], bOff[4][2];
  #pragma unroll
  for (int mi = 0; mi < 4; mi++){
    const int row = wv_m * 64 + mi * 16 + fr;
    #pragma unroll
    for (int ks = 0; ks < 2; ks++)
      aOff[mi][ks] = row * 128 + (((ks * 4 + fg) ^ (row & 7)) << 4);
  }
  #pragma unroll
  for (int nj = 0; nj < 4; nj++){
    const int row = wv_n * 64 + nj * 16 + fr;
    #pragma unroll
    for (int ks = 0; ks < 2; ks++)
      bOff[nj][ks] = 32768 + row * 128 + (((ks * 4 + fg) ^ (row & 7)) << 4);
  }

  f32x4 acc[4][4];
  #pragma unroll
  for (int i = 0; i < 4; i++)
    #pragma unroll
    for (int j = 0; j < 4; j++) acc[i][j] = (f32x4){0.f, 0.f, 0.f, 0.f};

#define STAGE_A(slotp, t, r) \
  gload_lds16(aP + rK64 * (r) + (size_t)(t) * 64, (slotp) + tid * 16 + (r) * 8192)
#define STAGE_B(slotp, t, r) \
  gload_lds16(bP + rK64 * (r) + (size_t)(t) * 64, (slotp) + 32768 + tid * 16 + (r) * 8192)

  const int nt = K >> 6;

  // prologue: stage tiles 0 and 1
  {
    char* s0 = lds_all;
    STAGE_A(s0, 0, 0); STAGE_A(s0, 0, 1); STAGE_B(s0, 0, 0);
    STAGE_A(s0, 0, 2); STAGE_A(s0, 0, 3); STAGE_B(s0, 0, 1);
    char* s1 = lds_all + 49152;
    STAGE_A(s1, 1, 0); STAGE_A(s1, 1, 1); STAGE_B(s1, 1, 0);
    STAGE_A(s1, 1, 2); STAGE_A(s1, 1, 3); STAGE_B(s1, 1, 1);
  }
  asm volatile("s_waitcnt vmcnt(6)" ::: "memory");
  __builtin_amdgcn_s_barrier();

  int st = 0;
  for (int t = 0; t < nt; t++){
    char* sA = lds_all + st * 49152;
    const int sg = (st >= 1) ? st - 1 : 2;      // (st+2) mod 3
    char* sG = lds_all + sg * 49152;
    const bool pf = (t + 2 < nt);

    // ---- phase 1: frags for mi 0..1, all B; stage 3 halves of tile t+2 ----
    short8 a0[2][2], bF[4][2];
    #pragma unroll
    for (int mi = 0; mi < 2; mi++)
      #pragma unroll
      for (int ks = 0; ks < 2; ks++)
        a0[mi][ks] = *(const short8*)(sA + aOff[mi][ks]);
    #pragma unroll
    for (int nj = 0; nj < 4; nj++)
      #pragma unroll
      for (int ks = 0; ks < 2; ks++)
        bF[nj][ks] = *(const short8*)(sA + bOff[nj][ks]);
    if (pf){
      STAGE_A(sG, t + 2, 0); STAGE_A(sG, t + 2, 1); STAGE_B(sG, t + 2, 0);
    }
    __builtin_amdgcn_s_barrier();
    asm volatile("s_waitcnt lgkmcnt(0)" ::: "memory");
    __builtin_amdgcn_sched_barrier(0);
    __builtin_amdgcn_s_setprio(1);
    #pragma unroll
    for (int mi = 0; mi < 2; mi++)
      #pragma unroll
      for (int nj = 0; nj < 4; nj++){
        acc[mi][nj] = mfma_bf16(a0[mi][0], bF[nj][0], acc[mi][nj]);
        acc[mi][nj] = mfma_bf16(a0[mi][1], bF[nj][1], acc[mi][nj]);
      }
    __builtin_amdgcn_s_setprio(0);
    __builtin_amdgcn_s_barrier();

    // ---- phase 2: frags for mi 2..3 (B reused); stage rest; vmcnt ----
    short8 a1[2][2];
    #pragma unroll
    for (int mi = 0; mi < 2; mi++)
      #pragma unroll
      for (int ks = 0; ks < 2; ks++)
        a1[mi][ks] = *(const short8*)(sA + aOff[2 + mi][ks]);
    if (pf){
      STAGE_A(sG, t + 2, 2); STAGE_A(sG, t + 2, 3); STAGE_B(sG, t + 2, 1);
      asm volatile("s_waitcnt vmcnt(6)" ::: "memory");
    } else {
      asm volatile("s_waitcnt vmcnt(0)" ::: "memory");
    }
    __builtin_amdgcn_s_barrier();
    asm volatile("s_waitcnt lgkmcnt(0)" ::: "memory");
    __builtin_amdgcn_sched_barrier(0);
    __builtin_amdgcn_s_setprio(1);
    #pragma unroll
    for (int mi = 0; mi < 2; mi++)
      #pragma unroll
      for (int nj = 0; nj < 4; nj++){
        acc[2 + mi][nj] = mfma_bf16(a1[mi][0], bF[nj][0], acc[2 + mi][nj]);
        acc[2 + mi][nj] = mfma_bf16(a1[mi][1], bF[nj][1], acc[2 + mi][nj]);
      }
    __builtin_amdgcn_s_setprio(0);
    __builtin_amdgcn_s_barrier();

    st = (st >= 2) ? 0 : st + 1;
  }
#undef STAGE_A
#undef STAGE_B

  // ---- epilogue ----
  #pragma unroll
  for (int mi = 0; mi < 4; mi++){
    const int mrow = m0 + wv_m * 64 + mi * 16 + fg * 4;
    #pragma unroll
    for (int nj = 0; nj < 4; nj++){
      const int ncol = n0 + wv_n * 64 + nj * 16 + fr;
      const float bv = bias[ncol];
      #pragma unroll
      for (int r2 = 0; r2 < 4; r2++){
        const size_t idx = (size_t)(mrow + r2) * N + ncol;
        float v = acc[mi][nj][r2] + bv;
        if (EPI == EPI_RESF32){
          ((float*)outp)[idx] = v + res[idx];
        } else if (EPI == EPI_GELU){
          const float tt = tanhf(0.7978845608028654f * (v + 0.044715f * v * v * v));
          ((unsigned short*)outp)[idx] = f2bf(0.5f * v * (1.0f + tt));
        } else {
          ((unsigned short*)outp)[idx] = f2bf(v);
        }
      }
    }
  }
}

// ===== causal flash attention (unchanged from round 2) =====
template<bool MASK>
__device__ __forceinline__ void attn_tile(
    const unsigned short* __restrict__ Kc, const unsigned short* __restrict__ Vc,
    const short8 (&qf)[4], int kvbase, int qg, int l31, int hi,
    float& m_r, float& lsum, f32x16& Oa, f32x16& Ob)
{
  f32x16 Sa = zero16();
  f32x16 Sb = zero16();
  const int xb = l31 & 7;
  #pragma unroll
  for (int kk = 0; kk < 4; kk++){
    const int x = kk * 2 + hi;
    const short8 k0 = *(const short8*)((const char*)Kc + l31 * 128 + ((x ^ xb) << 4));
    const short8 k1 = *(const short8*)((const char*)Kc + (l31 + 32) * 128 + ((x ^ xb) << 4));
    Sa = mfma32(k0, qf[kk], Sa);
    Sb = mfma32(k1, qf[kk], Sb);
  }
  if (MASK){
    #pragma unroll
    for (int r = 0; r < 16; r++){
      const int kva = kvbase + (r & 3) + 8 * (r >> 2) + 4 * hi;
      Sa[r] = (kva > qg)      ? -1e30f : Sa[r];
      Sb[r] = (kva + 32 > qg) ? -1e30f : Sb[r];
    }
  }
  float tmax = Sa[0];
  #pragma unroll
  for (int r = 1; r < 16; r++) tmax = fmaxf(tmax, Sa[r]);
  #pragma unroll
  for (int r = 0; r < 16; r++) tmax = fmaxf(tmax, Sb[r]);
  tmax = fmaxf(tmax, __shfl_xor(tmax, 32));
  if (__any(tmax > m_r + 10.0f)){
    const float mn = fmaxf(m_r, tmax);
    const float sc = exp2g(m_r - mn);
    m_r = mn;
    lsum *= sc;
    #pragma unroll
    for (int r = 0; r < 16; r++){ Oa[r] *= sc; Ob[r] *= sc; }
  }
  float rs = 0.0f;
  #pragma unroll
  for (int r = 0; r < 16; r++){
    Sa[r] = exp2g(Sa[r] - m_r); rs += Sa[r];
    Sb[r] = exp2g(Sb[r] - m_r); rs += Sb[r];
  }
  rs += __shfl_xor(rs, 32);
  lsum += rs;

  short8 pf[4];
  {
    uint32 a0 = cvtpk_bf(Sa[0], Sa[1]),   b0 = cvtpk_bf(Sa[4], Sa[5]);
    uint32 a1 = cvtpk_bf(Sa[2], Sa[3]),   b1 = cvtpk_bf(Sa[6], Sa[7]);
    plswap(a0, b0); plswap(a1, b1);
    uint32 a2 = cvtpk_bf(Sa[8], Sa[9]),   b2 = cvtpk_bf(Sa[12], Sa[13]);
    uint32 a3 = cvtpk_bf(Sa[10], Sa[11]), b3 = cvtpk_bf(Sa[14], Sa[15]);
    plswap(a2, b2); plswap(a3, b3);
    union { uint32 u[4]; short8 s; } m0, m1;
    m0.u[0] = a0; m0.u[1] = a1; m0.u[2] = b0; m0.u[3] = b1;
    m1.u[0] = a2; m1.u[1] = a3; m1.u[2] = b2; m1.u[3] = b3;
    pf[0] = m0.s; pf[1] = m1.s;
  }
  {
    uint32 a0 = cvtpk_bf(Sb[0], Sb[1]),   b0 = cvtpk_bf(Sb[4], Sb[5]);
    uint32 a1 = cvtpk_bf(Sb[2], Sb[3]),   b1 = cvtpk_bf(Sb[6], Sb[7]);
    plswap(a0, b0); plswap(a1, b1);
    uint32 a2 = cvtpk_bf(Sb[8], Sb[9]),   b2 = cvtpk_bf(Sb[12], Sb[13]);
    uint32 a3 = cvtpk_bf(Sb[10], Sb[11]), b3 = cvtpk_bf(Sb[14], Sb[15]);
    plswap(a2, b2); plswap(a3, b3);
    union { uint32 u[4]; short8 s; } m0, m1;
    m0.u[0] = a0; m0.u[1] = a1; m0.u[2] = b0; m0.u[3] = b1;
    m1.u[0] = a2; m1.u[1] = a3; m1.u[2] = b2; m1.u[3] = b3;
    pf[2] = m0.s; pf[3] = m1.s;
  }
  #pragma unroll
  for (int kk = 0; kk < 4; kk++){
    const int x = kk * 2 + hi;
    const short8 v0 = *(const short8*)((const char*)Vc + l31 * 128 + ((x ^ xb) << 4));
    const short8 v1 = *(const short8*)((const char*)Vc + (l31 + 32) * 128 + ((x ^ xb) << 4));
    Oa = mfma32(v0, pf[kk], Oa);
    Ob = mfma32(v1, pf[kk], Ob);
  }
}

__global__ __launch_bounds__(256) void attn_kernel(
    const unsigned short* __restrict__ qkv,
    const unsigned short* __restrict__ vt,
    unsigned short* __restrict__ y)
{
  __shared__ __align__(16) unsigned short Klds[2][4096];
  __shared__ __align__(16) unsigned short Vlds[2][4096];
  const int bid = blockIdx.x;
  const int bh = bid & 63;
  const int qb_i = bid >> 6;
  const int b = bh >> 4, h = bh & 15;
  const int qb0 = qb_i * 128;
  const int tid = threadIdx.x;
  const int w = tid >> 6;
  const int lane = tid & 63;
  const int l31 = lane & 31;
  const int hi = lane >> 5;

  const int qrow_g = b * 2048 + qb0 + w * 32 + l31;
  const unsigned short* qp = qkv + (size_t)qrow_g * 3072 + h * 64;
  short8 qf[4];
  #pragma unroll
  for (int kk = 0; kk < 4; kk++){
    short8 raw = *(const short8*)&qp[kk * 16 + hi * 8];
    #pragma unroll
    for (int j = 0; j < 8; j++)
      qf[kk][j] = (short)f2bf(bf2f((unsigned short)raw[j]) * 0.18033688011112042f);
  }

  const int sr = tid >> 3;
  const int ce = ((tid & 7) ^ (sr & 7)) * 8;
  const unsigned short* kb = qkv + (size_t)(b * 2048) * 3072 + 1024 + h * 64;
  const unsigned short* vb = vt + (size_t)bh * 64 * 2048;

  f32x16 Oa = zero16(), Ob = zero16();
  float m_r = -1e30f, lsum = 0.0f;
  const int qmin = qb0 + w * 32;
  const int qmax = qmin + 31;
  const int qg = qmin + l31;
  const int nkv = (qb0 >> 6) + 2;

#define STAGE(t, bb) do { \
    const size_t kro = (size_t)((t) * 64 + sr) * 3072; \
    gload_lds16(kb + kro + ce,                         (char*)&Klds[bb][0] + tid * 16); \
    gload_lds16(kb + kro + (size_t)32 * 3072 + ce,     (char*)&Klds[bb][0] + 4096 + tid * 16); \
    gload_lds16(vb + (size_t)sr * 2048 + (t) * 64 + ce,        (char*)&Vlds[bb][0] + tid * 16); \
    gload_lds16(vb + (size_t)(sr + 32) * 2048 + (t) * 64 + ce, (char*)&Vlds[bb][0] + 4096 + tid * 16); \
  } while (0)

  STAGE(0, 0);
  __syncthreads();
  int cur = 0;
  for (int kvt = 0; kvt < nkv; kvt++){
    if (kvt + 1 < nkv){
      if (cur) STAGE(kvt + 1, 0); else STAGE(kvt + 1, 1);
    }
    if (kvt * 64 <= qmax){
      if (kvt * 64 + 63 <= qmin)
        attn_tile<false>(Klds[cur], Vlds[cur], qf, kvt * 64, qg, l31, hi, m_r, lsum, Oa, Ob);
      else
        attn_tile<true >(Klds[cur], Vlds[cur], qf, kvt * 64, qg, l31, hi, m_r, lsum, Oa, Ob);
    }
    __syncthreads();
    cur ^= 1;
  }
#undef STAGE

  const float inv = 1.0f / lsum;
  unsigned short* yp = y + (size_t)qrow_g * 1024 + h * 64;
  #pragma unroll
  for (int c2 = 0; c2 < 4; c2++){
    uint2v da, db;
    da.x = cvtpk_bf(Oa[4 * c2 + 0] * inv, Oa[4 * c2 + 1] * inv);
    da.y = cvtpk_bf(Oa[4 * c2 + 2] * inv, Oa[4 * c2 + 3] * inv);
    *(uint2v*)&yp[8 * c2 + 4 * hi] = da;
    db.x = cvtpk_bf(Ob[4 * c2 + 0] * inv, Ob[4 * c2 + 1] * inv);
    db.y = cvtpk_bf(Ob[4 * c2 + 2] * inv, Ob[4 * c2 + 3] * inv);
    *(uint2v*)&yp[32 + 8 * c2 + 4 * hi] = db;
  }
}

// ===== launch =====
extern "C" void kernel_launch(void* const* d_in, const int* in_sizes, int n_in,
                              void* d_out, int out_size, void* d_ws, size_t ws_size,
                              hipStream_t stream)
{
  const float* x      = (const float*)d_in[0];
  const float* ln1_w  = (const float*)d_in[1];
  const float* ln1_b  = (const float*)d_in[2];
  const float* w_attn = (const float*)d_in[3];
  const float* b_attn = (const float*)d_in[4];
  const float* w_proj = (const float*)d_in[5];
  const float* b_proj = (const float*)d_in[6];
  const float* ln2_w  = (const float*)d_in[7];
  const float* ln2_b  = (const float*)d_in[8];
  const float* w_fc   = (const float*)d_in[9];
  const float* b_fc   = (const float*)d_in[10];
  const float* w_fc2  = (const float*)d_in[11];
  const float* b_fc2  = (const float*)d_in[12];

  char* ws = (char*)d_ws;
  unsigned short* wbT_attn = (unsigned short*)(ws + 0);          //  [3072][1024]
  unsigned short* wbT_proj = (unsigned short*)(ws + 6291456);    //  [1024][1024]
  unsigned short* wbT_fc   = (unsigned short*)(ws + 8388608);    //  [4096][1024]
  unsigned short* wbT_fc2  = (unsigned short*)(ws + 16777216);   //  [1024][4096]
  unsigned short* h_bf     = (unsigned short*)(ws + 25165824);   //  [8192][1024]
  unsigned short* qkv_bf   = (unsigned short*)(ws + 41943040);   //  [8192][3072]
  unsigned short* vt_bf    = (unsigned short*)(ws + 92274688);   //  [64][64][2048]
  unsigned short* g_bf     = (unsigned short*)(ws + 41943040);   //  alias qkv+vt: [8192][4096]
  unsigned short* y_bf     = (unsigned short*)(ws + 109051904);  //  [8192][1024]
  float*          x1       = (float*)(ws + 125829120);           //  [8192][1024]
  float* outf = (float*)d_out;

  wtrans_kernel<<<dim3(3072/32, 1024/32), 256, 0, stream>>>(w_attn, wbT_attn, 1024, 3072);
  wtrans_kernel<<<dim3(1024/32, 1024/32), 256, 0, stream>>>(w_proj, wbT_proj, 1024, 1024);
  wtrans_kernel<<<dim3(4096/32, 1024/32), 256, 0, stream>>>(w_fc,   wbT_fc,   1024, 4096);
  wtrans_kernel<<<dim3(1024/32, 4096/32), 256, 0, stream>>>(w_fc2,  wbT_fc2,  4096, 1024);

  // LN1: x -> h_bf
  ln_kernel<<<8192, 256, 0, stream>>>(x, ln1_w, ln1_b, h_bf);
  // qkv = h @ w_attn + b_attn   (grid = 32 m-tiles * 24 n-tiles)
  gemm2_kernel<EPI_BF16><<<32 * 24, 512, 0, stream>>>(
      h_bf, wbT_attn, b_attn, nullptr, qkv_bf, 8192, 3072, 1024);
  // V transpose for PV operand
  vtrans_kernel<<<dim3(64, 2, 64), 256, 0, stream>>>(qkv_bf, vt_bf);
  // causal flash attention -> y_bf
  attn_kernel<<<1024, 256, 0, stream>>>(qkv_bf, vt_bf, y_bf);
  // x1 = x + y @ w_proj + b_proj   (grid = 32 * 8)
  gemm2_kernel<EPI_RESF32><<<32 * 8, 512, 0, stream>>>(
      y_bf, wbT_proj, b_proj, x, x1, 8192, 1024, 1024);
  // LN2: x1 -> h_bf
  ln_kernel<<<8192, 256, 0, stream>>>(x1, ln2_w, ln2_b, h_bf);
  // g = gelu(h2 @ w_fc + b_fc)   (grid = 32 * 32)
  gemm2_kernel<EPI_GELU><<<32 * 32, 512, 0, stream>>>(
      h_bf, wbT_fc, b_fc, nullptr, g_bf, 8192, 4096, 1024);
  // out = x1 + g @ w_fc2 + b_fc2   (grid = 32 * 8)
  gemm2_kernel<EPI_RESF32><<<32 * 8, 512, 0, stream>>>(
      g_bf, wbT_fc2, b_fc2, x1, outf, 8192, 1024, 4096);
}

// Round 4
// 398.715 us; speedup vs baseline: 1.7244x; 1.0119x over previous
//
#include <hip/hip_runtime.h>

// ===== types =====
typedef __attribute__((ext_vector_type(8))) short short8;       // 8 x bf16 bits
typedef __attribute__((ext_vector_type(8))) unsigned short ushort8;
typedef __attribute__((ext_vector_type(4))) float f32x4;
typedef __attribute__((ext_vector_type(16))) float f32x16;
typedef __attribute__((ext_vector_type(2))) unsigned int uint2v;
typedef unsigned int uint32;

__device__ __forceinline__ unsigned short f2bf(float f){
  union { float f; unsigned int u; } x; x.f = f;
  unsigned int u = x.u;
  u += 0x7fffu + ((u >> 16) & 1u);   // RNE
  return (unsigned short)(u >> 16);
}
__device__ __forceinline__ float bf2f(unsigned short s){
  union { float f; unsigned int u; } x; x.u = ((uint32)s) << 16; return x.f;
}

typedef __attribute__((address_space(1))) void gvoid;
typedef __attribute__((address_space(3))) void lvoid;
__device__ __forceinline__ void gload_lds16(const void* g, void* l){
  __builtin_amdgcn_global_load_lds((gvoid*)g, (lvoid*)l, 16, 0, 0);
}

__device__ __forceinline__ f32x4 mfma_bf16(short8 a, short8 b, f32x4 c){
  return __builtin_amdgcn_mfma_f32_16x16x32_bf16(a, b, c, 0, 0, 0);
}
__device__ __forceinline__ f32x16 mfma32(short8 a, short8 b, f32x16 c){
  return __builtin_amdgcn_mfma_f32_32x32x16_bf16(a, b, c, 0, 0, 0);
}

__device__ __forceinline__ uint32 cvtpk_bf(float lo, float hi){
  uint32 r;
  asm("v_cvt_pk_bf16_f32 %0, %1, %2" : "=v"(r) : "v"(lo), "v"(hi));
  return r;
}
__device__ __forceinline__ void plswap(uint32& a, uint32& b){
  auto r = __builtin_amdgcn_permlane32_swap(a, b, false, false);
  a = r[0]; b = r[1];
}

#if __has_builtin(__builtin_amdgcn_exp2f)
__device__ __forceinline__ float exp2g(float x){ return __builtin_amdgcn_exp2f(x); }
#else
__device__ __forceinline__ float exp2g(float x){ return exp2f(x); }
#endif

__device__ __forceinline__ f32x16 zero16(){
  f32x16 z;
  #pragma unroll
  for (int i = 0; i < 16; i++) z[i] = 0.0f;
  return z;
}

// ===== weight transpose + fp32->bf16: w[K][N] -> wt[N][K] =====
__global__ __launch_bounds__(256) void wtrans_kernel(
    const float* __restrict__ w, unsigned short* __restrict__ wt, int K, int N)
{
  __shared__ float tile[32][33];
  const int n0 = blockIdx.x * 32;
  const int k0 = blockIdx.y * 32;
  const int t = threadIdx.x;
  #pragma unroll
  for (int i = 0; i < 4; i++){
    const int e = t + i * 256;
    const int r = e >> 5, c = e & 31;
    tile[r][c] = w[(size_t)(k0 + r) * N + n0 + c];
  }
  __syncthreads();
  #pragma unroll
  for (int i = 0; i < 4; i++){
    const int e = t + i * 256;
    const int r = e >> 5, c = e & 31;   // r = n-local, c = k-local
    wt[(size_t)(n0 + r) * K + k0 + c] = f2bf(tile[c][r]);
  }
}

// ===== V transpose: qkv[8192][3072] (v at col 2048+h*64) -> vt[bh][64][2048] bf16 =====
__global__ __launch_bounds__(256) void vtrans_kernel(
    const unsigned short* __restrict__ qkv, unsigned short* __restrict__ vt)
{
  __shared__ unsigned short tile[32][33];
  const int bh = blockIdx.z;
  const int b = bh >> 4, h = bh & 15;
  const int t0 = blockIdx.x * 32;
  const int f0 = blockIdx.y * 32;
  const int t = threadIdx.x;
  #pragma unroll
  for (int i = 0; i < 4; i++){
    const int e = t + i * 256;
    const int r = e >> 5, c = e & 31;   // r = t-local, c = feat-local
    tile[r][c] = qkv[(size_t)(b * 2048 + t0 + r) * 3072 + 2048 + h * 64 + f0 + c];
  }
  __syncthreads();
  #pragma unroll
  for (int i = 0; i < 4; i++){
    const int e = t + i * 256;
    const int r = e >> 5, c = e & 31;   // r = feat-local, c = t-local
    vt[((size_t)bh * 64 + f0 + r) * 2048 + t0 + c] = tile[c][r];
  }
}

// ===== LayerNorm fp32 -> bf16 (row = 1024) =====
__global__ __launch_bounds__(256) void ln_kernel(
    const float* __restrict__ x, const float* __restrict__ w, const float* __restrict__ b,
    unsigned short* __restrict__ out)
{
  const int row = blockIdx.x;
  const int t = threadIdx.x;
  const float4 v = ((const float4*)(x + (size_t)row * 1024))[t];
  float s  = v.x + v.y + v.z + v.w;
  float s2 = v.x * v.x + v.y * v.y + v.z * v.z + v.w * v.w;
  #pragma unroll
  for (int off = 32; off > 0; off >>= 1){
    s  += __shfl_xor(s, off);
    s2 += __shfl_xor(s2, off);
  }
  __shared__ float ps[8];
  const int wid = t >> 6;
  if ((t & 63) == 0){ ps[wid] = s; ps[4 + wid] = s2; }
  __syncthreads();
  s  = ps[0] + ps[1] + ps[2] + ps[3];
  s2 = ps[4] + ps[5] + ps[6] + ps[7];
  const float mu  = s * (1.0f / 1024.0f);
  const float var = s2 * (1.0f / 1024.0f) - mu * mu;
  const float rs  = rsqrtf(var + 1e-5f);
  const float4 wv = ((const float4*)w)[t];
  const float4 bv = ((const float4*)b)[t];
  ushort4 ov;
  ov.x = f2bf((v.x - mu) * rs * wv.x + bv.x);
  ov.y = f2bf((v.y - mu) * rs * wv.y + bv.y);
  ov.z = f2bf((v.z - mu) * rs * wv.z + bv.z);
  ov.w = f2bf((v.w - mu) * rs * wv.w + bv.w);
  ((ushort4*)(out + (size_t)row * 1024))[t] = ov;
}

// ===== GEMM v3: ring-3 counted-vmcnt, compiler-scheduled tile body =========
// C[M][N] = A[M][K](bf16) @ BT[N][K]^T + bias (+res / gelu).
// BM=256 BN=128 BK=64, 512 thr = 8 waves (4M x 2N), per-wave 64x64 acc[4][4].
// LDS ring of 3 slots (A 32KB + B 16KB each, 144KB). While computing tile t
// (slot t%3), stage tile t+2 into slot (t+2)%3 (dead since tile t-1) via
// global_load_lds(16B). ONE s_waitcnt vmcnt(6) + ONE s_barrier per K-tile:
// vmcnt(6) leaves tile t+2's 6 loads in flight, guarantees tile t+1 landed.
// NO lgkmcnt(0)/sched_barrier/phase-barriers inside the tile: the compiler
// emits fine-grained counted lgkm waits, interleaving the 16 ds_read_b128
// with the 32 MFMAs so LDS-read latency hides under MFMA (round-3's dual
// barrier phase-lock serialized these bursts -> 23% MfmaUtil).
// LDS 16B-slot XOR (row&7) swizzle, inverse-swizzled global source.
#define EPI_BF16   0
#define EPI_RESF32 1
#define EPI_GELU   2

template<int EPI>
__global__ __launch_bounds__(512) void gemm2_kernel(
    const unsigned short* __restrict__ A,
    const unsigned short* __restrict__ BT,
    const float* __restrict__ bias,
    const float* __restrict__ res,
    void* __restrict__ outp,
    int M, int N, int K)
{
  __shared__ __align__(16) char lds_all[3 * 49152];

  // XCD-aware bijective swizzle (nwg % 8 == 0 for all our shapes)
  const int nwg = gridDim.x;
  const int bid = blockIdx.x;
  const int wg = (bid & 7) * (nwg >> 3) + (bid >> 3);
  const int NT = N >> 7;
  const int mt = wg / NT;
  const int ntile = wg - mt * NT;
  const int m0 = mt << 8;
  const int n0 = ntile << 7;

  const int tid = threadIdx.x;
  const int lane = tid & 63;
  const int wid = tid >> 6;
  const int wv_m = wid >> 1;      // 0..3 -> 64-row band
  const int wv_n = wid & 1;       // 0..1 -> 64-col band
  const int fr = lane & 15;
  const int fg = lane >> 4;

  // staging geometry: thread -> (row = tid>>3 within 64-row chunk, 16B slot)
  const int srow = tid >> 3;
  const int scol = ((tid & 7) ^ (srow & 7)) << 3;    // inverse-swizzled source col
  const unsigned short* aP = A  + (size_t)(m0 + srow) * K + scol;
  const unsigned short* bP = BT + (size_t)(n0 + srow) * K + scol;
  const size_t rK64 = (size_t)64 * K;

  // LDS read offsets (precomputed, tile-slot-relative)
  int aOff[4][2], bOff[4][2];
  #pragma unroll
  for (int mi = 0; mi < 4; mi++){
    const int row = wv_m * 64 + mi * 16 + fr;
    #pragma unroll
    for (int ks = 0; ks < 2; ks++)
      aOff[mi][ks] = row * 128 + (((ks * 4 + fg) ^ (row & 7)) << 4);
  }
  #pragma unroll
  for (int nj = 0; nj < 4; nj++){
    const int row = wv_n * 64 + nj * 16 + fr;
    #pragma unroll
    for (int ks = 0; ks < 2; ks++)
      bOff[nj][ks] = 32768 + row * 128 + (((ks * 4 + fg) ^ (row & 7)) << 4);
  }

  f32x4 acc[4][4];
  #pragma unroll
  for (int i = 0; i < 4; i++)
    #pragma unroll
    for (int j = 0; j < 4; j++) acc[i][j] = (f32x4){0.f, 0.f, 0.f, 0.f};

#define STAGE_A(slotp, t, r) \
  gload_lds16(aP + rK64 * (r) + (size_t)(t) * 64, (slotp) + tid * 16 + (r) * 8192)
#define STAGE_B(slotp, t, r) \
  gload_lds16(bP + rK64 * (r) + (size_t)(t) * 64, (slotp) + 32768 + tid * 16 + (r) * 8192)

  const int nt = K >> 6;

  // prologue: stage tiles 0 and 1
  {
    char* s0 = lds_all;
    STAGE_A(s0, 0, 0); STAGE_A(s0, 0, 1); STAGE_B(s0, 0, 0);
    STAGE_A(s0, 0, 2); STAGE_A(s0, 0, 3); STAGE_B(s0, 0, 1);
    char* s1 = lds_all + 49152;
    STAGE_A(s1, 1, 0); STAGE_A(s1, 1, 1); STAGE_B(s1, 1, 0);
    STAGE_A(s1, 1, 2); STAGE_A(s1, 1, 3); STAGE_B(s1, 1, 1);
  }
  asm volatile("s_waitcnt vmcnt(6)" ::: "memory");
  __builtin_amdgcn_s_barrier();
  asm volatile("" ::: "memory");

  int st = 0;
  for (int t = 0; t < nt; t++){
    char* sA = lds_all + st * 49152;
    const int sg = (st >= 1) ? st - 1 : 2;      // (st+2) mod 3
    char* sG = lds_all + sg * 49152;
    const bool pf = (t + 2 < nt);

    // issue next-next tile's staging first (latency hides under this tile)
    if (pf){
      STAGE_A(sG, t + 2, 0); STAGE_A(sG, t + 2, 1); STAGE_B(sG, t + 2, 0);
      STAGE_A(sG, t + 2, 2); STAGE_A(sG, t + 2, 3); STAGE_B(sG, t + 2, 1);
    }

    // tile body: reads + MFMAs, compiler-interleaved (counted lgkm waits)
    short8 a0[2][2], a1[2][2], bF[4][2];
    #pragma unroll
    for (int mi = 0; mi < 2; mi++)
      #pragma unroll
      for (int ks = 0; ks < 2; ks++)
        a0[mi][ks] = *(const short8*)(sA + aOff[mi][ks]);
    #pragma unroll
    for (int nj = 0; nj < 4; nj++)
      #pragma unroll
      for (int ks = 0; ks < 2; ks++)
        bF[nj][ks] = *(const short8*)(sA + bOff[nj][ks]);
    #pragma unroll
    for (int mi = 0; mi < 2; mi++)
      #pragma unroll
      for (int nj = 0; nj < 4; nj++){
        acc[mi][nj] = mfma_bf16(a0[mi][0], bF[nj][0], acc[mi][nj]);
        acc[mi][nj] = mfma_bf16(a0[mi][1], bF[nj][1], acc[mi][nj]);
      }
    #pragma unroll
    for (int mi = 0; mi < 2; mi++)
      #pragma unroll
      for (int ks = 0; ks < 2; ks++)
        a1[mi][ks] = *(const short8*)(sA + aOff[2 + mi][ks]);
    #pragma unroll
    for (int mi = 0; mi < 2; mi++)
      #pragma unroll
      for (int nj = 0; nj < 4; nj++){
        acc[2 + mi][nj] = mfma_bf16(a1[mi][0], bF[nj][0], acc[2 + mi][nj]);
        acc[2 + mi][nj] = mfma_bf16(a1[mi][1], bF[nj][1], acc[2 + mi][nj]);
      }

    if (pf){
      asm volatile("s_waitcnt vmcnt(6)" ::: "memory");
    } else {
      asm volatile("s_waitcnt vmcnt(0)" ::: "memory");
    }
    __builtin_amdgcn_s_barrier();
    asm volatile("" ::: "memory");

    st = (st >= 2) ? 0 : st + 1;
  }
#undef STAGE_A
#undef STAGE_B

  // ---- epilogue ----
  #pragma unroll
  for (int mi = 0; mi < 4; mi++){
    const int mrow = m0 + wv_m * 64 + mi * 16 + fg * 4;
    #pragma unroll
    for (int nj = 0; nj < 4; nj++){
      const int ncol = n0 + wv_n * 64 + nj * 16 + fr;
      const float bv = bias[ncol];
      #pragma unroll
      for (int r2 = 0; r2 < 4; r2++){
        const size_t idx = (size_t)(mrow + r2) * N + ncol;
        float v = acc[mi][nj][r2] + bv;
        if (EPI == EPI_RESF32){
          ((float*)outp)[idx] = v + res[idx];
        } else if (EPI == EPI_GELU){
          const float tt = tanhf(0.7978845608028654f * (v + 0.044715f * v * v * v));
          ((unsigned short*)outp)[idx] = f2bf(0.5f * v * (1.0f + tt));
        } else {
          ((unsigned short*)outp)[idx] = f2bf(v);
        }
      }
    }
  }
}

// ===== causal flash attention (unchanged from round 2) =====
template<bool MASK>
__device__ __forceinline__ void attn_tile(
    const unsigned short* __restrict__ Kc, const unsigned short* __restrict__ Vc,
    const short8 (&qf)[4], int kvbase, int qg, int l31, int hi,
    float& m_r, float& lsum, f32x16& Oa, f32x16& Ob)
{
  f32x16 Sa = zero16();
  f32x16 Sb = zero16();
  const int xb = l31 & 7;
  #pragma unroll
  for (int kk = 0; kk < 4; kk++){
    const int x = kk * 2 + hi;
    const short8 k0 = *(const short8*)((const char*)Kc + l31 * 128 + ((x ^ xb) << 4));
    const short8 k1 = *(const short8*)((const char*)Kc + (l31 + 32) * 128 + ((x ^ xb) << 4));
    Sa = mfma32(k0, qf[kk], Sa);
    Sb = mfma32(k1, qf[kk], Sb);
  }
  if (MASK){
    #pragma unroll
    for (int r = 0; r < 16; r++){
      const int kva = kvbase + (r & 3) + 8 * (r >> 2) + 4 * hi;
      Sa[r] = (kva > qg)      ? -1e30f : Sa[r];
      Sb[r] = (kva + 32 > qg) ? -1e30f : Sb[r];
    }
  }
  float tmax = Sa[0];
  #pragma unroll
  for (int r = 1; r < 16; r++) tmax = fmaxf(tmax, Sa[r]);
  #pragma unroll
  for (int r = 0; r < 16; r++) tmax = fmaxf(tmax, Sb[r]);
  tmax = fmaxf(tmax, __shfl_xor(tmax, 32));
  if (__any(tmax > m_r + 10.0f)){
    const float mn = fmaxf(m_r, tmax);
    const float sc = exp2g(m_r - mn);
    m_r = mn;
    lsum *= sc;
    #pragma unroll
    for (int r = 0; r < 16; r++){ Oa[r] *= sc; Ob[r] *= sc; }
  }
  float rs = 0.0f;
  #pragma unroll
  for (int r = 0; r < 16; r++){
    Sa[r] = exp2g(Sa[r] - m_r); rs += Sa[r];
    Sb[r] = exp2g(Sb[r] - m_r); rs += Sb[r];
  }
  rs += __shfl_xor(rs, 32);
  lsum += rs;

  short8 pf[4];
  {
    uint32 a0 = cvtpk_bf(Sa[0], Sa[1]),   b0 = cvtpk_bf(Sa[4], Sa[5]);
    uint32 a1 = cvtpk_bf(Sa[2], Sa[3]),   b1 = cvtpk_bf(Sa[6], Sa[7]);
    plswap(a0, b0); plswap(a1, b1);
    uint32 a2 = cvtpk_bf(Sa[8], Sa[9]),   b2 = cvtpk_bf(Sa[12], Sa[13]);
    uint32 a3 = cvtpk_bf(Sa[10], Sa[11]), b3 = cvtpk_bf(Sa[14], Sa[15]);
    plswap(a2, b2); plswap(a3, b3);
    union { uint32 u[4]; short8 s; } m0, m1;
    m0.u[0] = a0; m0.u[1] = a1; m0.u[2] = b0; m0.u[3] = b1;
    m1.u[0] = a2; m1.u[1] = a3; m1.u[2] = b2; m1.u[3] = b3;
    pf[0] = m0.s; pf[1] = m1.s;
  }
  {
    uint32 a0 = cvtpk_bf(Sb[0], Sb[1]),   b0 = cvtpk_bf(Sb[4], Sb[5]);
    uint32 a1 = cvtpk_bf(Sb[2], Sb[3]),   b1 = cvtpk_bf(Sb[6], Sb[7]);
    plswap(a0, b0); plswap(a1, b1);
    uint32 a2 = cvtpk_bf(Sb[8], Sb[9]),   b2 = cvtpk_bf(Sb[12], Sb[13]);
    uint32 a3 = cvtpk_bf(Sb[10], Sb[11]), b3 = cvtpk_bf(Sb[14], Sb[15]);
    plswap(a2, b2); plswap(a3, b3);
    union { uint32 u[4]; short8 s; } m0, m1;
    m0.u[0] = a0; m0.u[1] = a1; m0.u[2] = b0; m0.u[3] = b1;
    m1.u[0] = a2; m1.u[1] = a3; m1.u[2] = b2; m1.u[3] = b3;
    pf[2] = m0.s; pf[3] = m1.s;
  }
  #pragma unroll
  for (int kk = 0; kk < 4; kk++){
    const int x = kk * 2 + hi;
    const short8 v0 = *(const short8*)((const char*)Vc + l31 * 128 + ((x ^ xb) << 4));
    const short8 v1 = *(const short8*)((const char*)Vc + (l31 + 32) * 128 + ((x ^ xb) << 4));
    Oa = mfma32(v0, pf[kk], Oa);
    Ob = mfma32(v1, pf[kk], Ob);
  }
}

__global__ __launch_bounds__(256) void attn_kernel(
    const unsigned short* __restrict__ qkv,
    const unsigned short* __restrict__ vt,
    unsigned short* __restrict__ y)
{
  __shared__ __align__(16) unsigned short Klds[2][4096];
  __shared__ __align__(16) unsigned short Vlds[2][4096];
  const int bid = blockIdx.x;
  const int bh = bid & 63;
  const int qb_i = bid >> 6;
  const int b = bh >> 4, h = bh & 15;
  const int qb0 = qb_i * 128;
  const int tid = threadIdx.x;
  const int w = tid >> 6;
  const int lane = tid & 63;
  const int l31 = lane & 31;
  const int hi = lane >> 5;

  const int qrow_g = b * 2048 + qb0 + w * 32 + l31;
  const unsigned short* qp = qkv + (size_t)qrow_g * 3072 + h * 64;
  short8 qf[4];
  #pragma unroll
  for (int kk = 0; kk < 4; kk++){
    short8 raw = *(const short8*)&qp[kk * 16 + hi * 8];
    #pragma unroll
    for (int j = 0; j < 8; j++)
      qf[kk][j] = (short)f2bf(bf2f((unsigned short)raw[j]) * 0.18033688011112042f);
  }

  const int sr = tid >> 3;
  const int ce = ((tid & 7) ^ (sr & 7)) * 8;
  const unsigned short* kb = qkv + (size_t)(b * 2048) * 3072 + 1024 + h * 64;
  const unsigned short* vb = vt + (size_t)bh * 64 * 2048;

  f32x16 Oa = zero16(), Ob = zero16();
  float m_r = -1e30f, lsum = 0.0f;
  const int qmin = qb0 + w * 32;
  const int qmax = qmin + 31;
  const int qg = qmin + l31;
  const int nkv = (qb0 >> 6) + 2;

#define STAGE(t, bb) do { \
    const size_t kro = (size_t)((t) * 64 + sr) * 3072; \
    gload_lds16(kb + kro + ce,                         (char*)&Klds[bb][0] + tid * 16); \
    gload_lds16(kb + kro + (size_t)32 * 3072 + ce,     (char*)&Klds[bb][0] + 4096 + tid * 16); \
    gload_lds16(vb + (size_t)sr * 2048 + (t) * 64 + ce,        (char*)&Vlds[bb][0] + tid * 16); \
    gload_lds16(vb + (size_t)(sr + 32) * 2048 + (t) * 64 + ce, (char*)&Vlds[bb][0] + 4096 + tid * 16); \
  } while (0)

  STAGE(0, 0);
  __syncthreads();
  int cur = 0;
  for (int kvt = 0; kvt < nkv; kvt++){
    if (kvt + 1 < nkv){
      if (cur) STAGE(kvt + 1, 0); else STAGE(kvt + 1, 1);
    }
    if (kvt * 64 <= qmax){
      if (kvt * 64 + 63 <= qmin)
        attn_tile<false>(Klds[cur], Vlds[cur], qf, kvt * 64, qg, l31, hi, m_r, lsum, Oa, Ob);
      else
        attn_tile<true >(Klds[cur], Vlds[cur], qf, kvt * 64, qg, l31, hi, m_r, lsum, Oa, Ob);
    }
    __syncthreads();
    cur ^= 1;
  }
#undef STAGE

  const float inv = 1.0f / lsum;
  unsigned short* yp = y + (size_t)qrow_g * 1024 + h * 64;
  #pragma unroll
  for (int c2 = 0; c2 < 4; c2++){
    uint2v da, db;
    da.x = cvtpk_bf(Oa[4 * c2 + 0] * inv, Oa[4 * c2 + 1] * inv);
    da.y = cvtpk_bf(Oa[4 * c2 + 2] * inv, Oa[4 * c2 + 3] * inv);
    *(uint2v*)&yp[8 * c2 + 4 * hi] = da;
    db.x = cvtpk_bf(Ob[4 * c2 + 0] * inv, Ob[4 * c2 + 1] * inv);
    db.y = cvtpk_bf(Ob[4 * c2 + 2] * inv, Ob[4 * c2 + 3] * inv);
    *(uint2v*)&yp[32 + 8 * c2 + 4 * hi] = db;
  }
}

// ===== launch =====
extern "C" void kernel_launch(void* const* d_in, const int* in_sizes, int n_in,
                              void* d_out, int out_size, void* d_ws, size_t ws_size,
                              hipStream_t stream)
{
  const float* x      = (const float*)d_in[0];
  const float* ln1_w  = (const float*)d_in[1];
  const float* ln1_b  = (const float*)d_in[2];
  const float* w_attn = (const float*)d_in[3];
  const float* b_attn = (const float*)d_in[4];
  const float* w_proj = (const float*)d_in[5];
  const float* b_proj = (const float*)d_in[6];
  const float* ln2_w  = (const float*)d_in[7];
  const float* ln2_b  = (const float*)d_in[8];
  const float* w_fc   = (const float*)d_in[9];
  const float* b_fc   = (const float*)d_in[10];
  const float* w_fc2  = (const float*)d_in[11];
  const float* b_fc2  = (const float*)d_in[12];

  char* ws = (char*)d_ws;
  unsigned short* wbT_attn = (unsigned short*)(ws + 0);          //  [3072][1024]
  unsigned short* wbT_proj = (unsigned short*)(ws + 6291456);    //  [1024][1024]
  unsigned short* wbT_fc   = (unsigned short*)(ws + 8388608);    //  [4096][1024]
  unsigned short* wbT_fc2  = (unsigned short*)(ws + 16777216);   //  [1024][4096]
  unsigned short* h_bf     = (unsigned short*)(ws + 25165824);   //  [8192][1024]
  unsigned short* qkv_bf   = (unsigned short*)(ws + 41943040);   //  [8192][3072]
  unsigned short* vt_bf    = (unsigned short*)(ws + 92274688);   //  [64][64][2048]
  unsigned short* g_bf     = (unsigned short*)(ws + 41943040);   //  alias qkv+vt: [8192][4096]
  unsigned short* y_bf     = (unsigned short*)(ws + 109051904);  //  [8192][1024]
  float*          x1       = (float*)(ws + 125829120);           //  [8192][1024]
  float* outf = (float*)d_out;

  wtrans_kernel<<<dim3(3072/32, 1024/32), 256, 0, stream>>>(w_attn, wbT_attn, 1024, 3072);
  wtrans_kernel<<<dim3(1024/32, 1024/32), 256, 0, stream>>>(w_proj, wbT_proj, 1024, 1024);
  wtrans_kernel<<<dim3(4096/32, 1024/32), 256, 0, stream>>>(w_fc,   wbT_fc,   1024, 4096);
  wtrans_kernel<<<dim3(1024/32, 4096/32), 256, 0, stream>>>(w_fc2,  wbT_fc2,  4096, 1024);

  // LN1: x -> h_bf
  ln_kernel<<<8192, 256, 0, stream>>>(x, ln1_w, ln1_b, h_bf);
  // qkv = h @ w_attn + b_attn   (grid = 32 m-tiles * 24 n-tiles)
  gemm2_kernel<EPI_BF16><<<32 * 24, 512, 0, stream>>>(
      h_bf, wbT_attn, b_attn, nullptr, qkv_bf, 8192, 3072, 1024);
  // V transpose for PV operand
  vtrans_kernel<<<dim3(64, 2, 64), 256, 0, stream>>>(qkv_bf, vt_bf);
  // causal flash attention -> y_bf
  attn_kernel<<<1024, 256, 0, stream>>>(qkv_bf, vt_bf, y_bf);
  // x1 = x + y @ w_proj + b_proj   (grid = 32 * 8)
  gemm2_kernel<EPI_RESF32><<<32 * 8, 512, 0, stream>>>(
      y_bf, wbT_proj, b_proj, x, x1, 8192, 1024, 1024);
  // LN2: x1 -> h_bf
  ln_kernel<<<8192, 256, 0, stream>>>(x1, ln2_w, ln2_b, h_bf);
  // g = gelu(h2 @ w_fc + b_fc)   (grid = 32 * 32)
  gemm2_kernel<EPI_GELU><<<32 * 32, 512, 0, stream>>>(
      h_bf, wbT_fc, b_fc, nullptr, g_bf, 8192, 4096, 1024);
  // out = x1 + g @ w_fc2 + b_fc2   (grid = 32 * 8)
  gemm2_kernel<EPI_RESF32><<<32 * 8, 512, 0, stream>>>(
      g_bf, wbT_fc2, b_fc2, x1, outf, 8192, 1024, 4096);
}

// Round 5
// 393.853 us; speedup vs baseline: 1.7456x; 1.0123x over previous
//
#include <hip/hip_runtime.h>

// ===== types =====
typedef __attribute__((ext_vector_type(8))) short short8;       // 8 x bf16 bits
typedef __attribute__((ext_vector_type(8))) unsigned short ushort8;
typedef __attribute__((ext_vector_type(4))) float f32x4;
typedef __attribute__((ext_vector_type(16))) float f32x16;
typedef __attribute__((ext_vector_type(2))) unsigned int uint2v;
typedef unsigned int uint32;

__device__ __forceinline__ unsigned short f2bf(float f){
  union { float f; unsigned int u; } x; x.f = f;
  unsigned int u = x.u;
  u += 0x7fffu + ((u >> 16) & 1u);   // RNE
  return (unsigned short)(u >> 16);
}
__device__ __forceinline__ float bf2f(unsigned short s){
  union { float f; unsigned int u; } x; x.u = ((uint32)s) << 16; return x.f;
}

typedef __attribute__((address_space(1))) void gvoid;
typedef __attribute__((address_space(3))) void lvoid;
__device__ __forceinline__ void gload_lds16(const void* g, void* l){
  __builtin_amdgcn_global_load_lds((gvoid*)g, (lvoid*)l, 16, 0, 0);
}

__device__ __forceinline__ f32x4 mfma_bf16(short8 a, short8 b, f32x4 c){
  return __builtin_amdgcn_mfma_f32_16x16x32_bf16(a, b, c, 0, 0, 0);
}
__device__ __forceinline__ f32x16 mfma32(short8 a, short8 b, f32x16 c){
  return __builtin_amdgcn_mfma_f32_32x32x16_bf16(a, b, c, 0, 0, 0);
}

__device__ __forceinline__ uint32 cvtpk_bf(float lo, float hi){
  uint32 r;
  asm("v_cvt_pk_bf16_f32 %0, %1, %2" : "=v"(r) : "v"(lo), "v"(hi));
  return r;
}
__device__ __forceinline__ void plswap(uint32& a, uint32& b){
  auto r = __builtin_amdgcn_permlane32_swap(a, b, false, false);
  a = r[0]; b = r[1];
}

#if __has_builtin(__builtin_amdgcn_exp2f)
__device__ __forceinline__ float exp2g(float x){ return __builtin_amdgcn_exp2f(x); }
#else
__device__ __forceinline__ float exp2g(float x){ return exp2f(x); }
#endif

__device__ __forceinline__ f32x16 zero16(){
  f32x16 z;
  #pragma unroll
  for (int i = 0; i < 16; i++) z[i] = 0.0f;
  return z;
}

// ===== weight transpose + fp32->bf16: w[K][N] -> wt[N][K] =====
__global__ __launch_bounds__(256) void wtrans_kernel(
    const float* __restrict__ w, unsigned short* __restrict__ wt, int K, int N)
{
  __shared__ float tile[32][33];
  const int n0 = blockIdx.x * 32;
  const int k0 = blockIdx.y * 32;
  const int t = threadIdx.x;
  #pragma unroll
  for (int i = 0; i < 4; i++){
    const int e = t + i * 256;
    const int r = e >> 5, c = e & 31;
    tile[r][c] = w[(size_t)(k0 + r) * N + n0 + c];
  }
  __syncthreads();
  #pragma unroll
  for (int i = 0; i < 4; i++){
    const int e = t + i * 256;
    const int r = e >> 5, c = e & 31;   // r = n-local, c = k-local
    wt[(size_t)(n0 + r) * K + k0 + c] = f2bf(tile[c][r]);
  }
}

// ===== V transpose: qkv[8192][3072] (v at col 2048+h*64) -> vt[bh][64][2048] bf16 =====
__global__ __launch_bounds__(256) void vtrans_kernel(
    const unsigned short* __restrict__ qkv, unsigned short* __restrict__ vt)
{
  __shared__ unsigned short tile[32][33];
  const int bh = blockIdx.z;
  const int b = bh >> 4, h = bh & 15;
  const int t0 = blockIdx.x * 32;
  const int f0 = blockIdx.y * 32;
  const int t = threadIdx.x;
  #pragma unroll
  for (int i = 0; i < 4; i++){
    const int e = t + i * 256;
    const int r = e >> 5, c = e & 31;   // r = t-local, c = feat-local
    tile[r][c] = qkv[(size_t)(b * 2048 + t0 + r) * 3072 + 2048 + h * 64 + f0 + c];
  }
  __syncthreads();
  #pragma unroll
  for (int i = 0; i < 4; i++){
    const int e = t + i * 256;
    const int r = e >> 5, c = e & 31;   // r = feat-local, c = t-local
    vt[((size_t)bh * 64 + f0 + r) * 2048 + t0 + c] = tile[c][r];
  }
}

// ===== LayerNorm fp32 -> bf16 (row = 1024) =====
__global__ __launch_bounds__(256) void ln_kernel(
    const float* __restrict__ x, const float* __restrict__ w, const float* __restrict__ b,
    unsigned short* __restrict__ out)
{
  const int row = blockIdx.x;
  const int t = threadIdx.x;
  const float4 v = ((const float4*)(x + (size_t)row * 1024))[t];
  float s  = v.x + v.y + v.z + v.w;
  float s2 = v.x * v.x + v.y * v.y + v.z * v.z + v.w * v.w;
  #pragma unroll
  for (int off = 32; off > 0; off >>= 1){
    s  += __shfl_xor(s, off);
    s2 += __shfl_xor(s2, off);
  }
  __shared__ float ps[8];
  const int wid = t >> 6;
  if ((t & 63) == 0){ ps[wid] = s; ps[4 + wid] = s2; }
  __syncthreads();
  s  = ps[0] + ps[1] + ps[2] + ps[3];
  s2 = ps[4] + ps[5] + ps[6] + ps[7];
  const float mu  = s * (1.0f / 1024.0f);
  const float var = s2 * (1.0f / 1024.0f) - mu * mu;
  const float rs  = rsqrtf(var + 1e-5f);
  const float4 wv = ((const float4*)w)[t];
  const float4 bv = ((const float4*)b)[t];
  ushort4 ov;
  ov.x = f2bf((v.x - mu) * rs * wv.x + bv.x);
  ov.y = f2bf((v.y - mu) * rs * wv.y + bv.y);
  ov.z = f2bf((v.z - mu) * rs * wv.z + bv.z);
  ov.w = f2bf((v.w - mu) * rs * wv.w + bv.w);
  ((ushort4*)(out + (size_t)row * 1024))[t] = ov;
}

// ===== GEMM v4: m201-geometry port ========================================
// C[M][N] = A[M][K](bf16) @ BT[N][K]^T + bias (+res / gelu).
// BM=256, BK=64, 512 thr = 8 waves (2 wv_m x 4 wv_n), per-wave 128 x BN/4.
// BN=256: per-wave 128x64 (24 ds_read / 64 MFMA per wave-tile -> LDS 2304 cyc
// vs MFMA 2483 cyc per block-tile, balanced). BN=128 (for N=1024, grid=256).
// LDS per buf: A 2 K-slices x [256 rows][32k=64B], B 2 slices x [BN][64B];
// 2-deep dbuf (128/96 KB). 2 phases per K-tile (one per K=32 slice):
//   {12 ds_read || stage next-tile slice-pair -> barrier -> lgkmcnt(0)
//    -> sched_barrier -> setprio(1) -> 8xNJ MFMA -> setprio(0)
//    -> vmcnt(LPP) -> barrier}
// Stage->consume distance = 2 phases uniformly; end-of-phase vmcnt(LPP)
// guarantees the previous phase's slice landed (never drains to 0).
// Swizzle: slot = fg ^ ((row>>1)&3) within 4x16B slots/row -> parity-balanced
// 2-way max (free); inverse-swizzled global source (both-sides rule).
#define EPI_BF16   0
#define EPI_RESF32 1
#define EPI_GELU   2

template<int EPI, int BN>
__global__ __launch_bounds__(512, 2) void gemm3_kernel(
    const unsigned short* __restrict__ A,
    const unsigned short* __restrict__ BT,
    const float* __restrict__ bias,
    const float* __restrict__ res,
    void* __restrict__ outp,
    int M, int N, int K)
{
  constexpr int NJ   = BN / 64;            // B-frags per wave per slice
  constexpr int BSL  = BN * 64;            // B slice bytes
  constexpr int SBUF = 32768 + 2 * BSL;    // per-buffer bytes
  constexpr int NBL  = BN / 128;           // B stage loads per slice (1 or 2)
  __shared__ __align__(16) char lds[2 * SBUF];

  // XCD-aware bijective swizzle (nwg % 8 == 0 for all shapes used)
  const int nwg = gridDim.x;
  const int bid = blockIdx.x;
  const int wg = (bid & 7) * (nwg >> 3) + (bid >> 3);
  const int NTile = N / BN;
  const int mt = wg / NTile;
  const int nti = wg - mt * NTile;
  const int m0 = mt << 8;
  const int n0 = nti * BN;

  const int tid = threadIdx.x;
  const int lane = tid & 63;
  const int wid = tid >> 6;
  const int wv_m = wid >> 2;     // 0..1 -> 128-row band
  const int wv_n = wid & 3;      // 0..3 -> (BN/4)-col band
  const int fr = lane & 15;
  const int fg = lane >> 4;

  // ---- staging geometry (slot s -> row=s>>2, c=s&3; inverse-swizzled src) --
  const unsigned short* aSrc[2];
  int aDst[2];
  #pragma unroll
  for (int l = 0; l < 2; l++){
    const int s = l * 512 + tid;
    const int r = s >> 2, c = s & 3;
    aSrc[l] = A + (size_t)(m0 + r) * K + ((c ^ ((r >> 1) & 3)) << 3);
    aDst[l] = s * 16;
  }
  const unsigned short* bSrc[2];
  int bDst[2];
  #pragma unroll
  for (int l = 0; l < NBL; l++){
    const int s = l * 512 + tid;
    const int r = s >> 2, c = s & 3;
    bSrc[l] = BT + (size_t)(n0 + r) * K + ((c ^ ((r >> 1) & 3)) << 3);
    bDst[l] = 32768 + s * 16;
  }

  // ---- fragment read offsets (slice-relative, swizzled) ----
  int aOff[8], bOff[NJ];
  #pragma unroll
  for (int mi = 0; mi < 8; mi++){
    const int row = wv_m * 128 + mi * 16 + fr;
    aOff[mi] = row * 64 + ((fg ^ ((row >> 1) & 3)) << 4);
  }
  #pragma unroll
  for (int nj = 0; nj < NJ; nj++){
    const int row = wv_n * (BN / 4) + nj * 16 + fr;
    bOff[nj] = 32768 + row * 64 + ((fg ^ ((row >> 1) & 3)) << 4);
  }

  f32x4 acc[8][NJ];
  #pragma unroll
  for (int i = 0; i < 8; i++)
    #pragma unroll
    for (int j = 0; j < NJ; j++) acc[i][j] = (f32x4){0.f, 0.f, 0.f, 0.f};

#define STAGE(tt, kss, bufc) do { \
    const size_t ko = (size_t)(tt) * 64 + (kss) * 32; \
    gload_lds16(aSrc[0] + ko, lds + (bufc) + (kss) * 16384 + aDst[0]); \
    gload_lds16(aSrc[1] + ko, lds + (bufc) + (kss) * 16384 + aDst[1]); \
    gload_lds16(bSrc[0] + ko, lds + (bufc) + (kss) * BSL + bDst[0]); \
    if (NBL == 2) gload_lds16(bSrc[1] + ko, lds + (bufc) + (kss) * BSL + bDst[1]); \
  } while (0)

  const int nt = K >> 6;

  // prologue: stage tile 0 (both slices) into buf0
  STAGE(0, 0, 0);
  STAGE(0, 1, 0);
  if (BN == 256) asm volatile("s_waitcnt vmcnt(4)" ::: "memory");
  else           asm volatile("s_waitcnt vmcnt(3)" ::: "memory");
  __builtin_amdgcn_s_barrier();

  int bufc = 0;
  for (int t = 0; t < nt; t++){
    const int obuf = bufc ^ SBUF;
    const bool pf = (t + 1 < nt);
    #pragma unroll
    for (int ks = 0; ks < 2; ks++){
      short8 aF[8], bF[NJ];
      #pragma unroll
      for (int mi = 0; mi < 8; mi++)
        aF[mi] = *(const short8*)(lds + bufc + ks * 16384 + aOff[mi]);
      #pragma unroll
      for (int nj = 0; nj < NJ; nj++)
        bF[nj] = *(const short8*)(lds + bufc + ks * BSL + bOff[nj]);
      if (pf) STAGE(t + 1, ks, obuf);
      __builtin_amdgcn_s_barrier();
      asm volatile("s_waitcnt lgkmcnt(0)" ::: "memory");
      __builtin_amdgcn_sched_barrier(0);
      __builtin_amdgcn_s_setprio(1);
      #pragma unroll
      for (int mi = 0; mi < 8; mi++)
        #pragma unroll
        for (int nj = 0; nj < NJ; nj++)
          acc[mi][nj] = mfma_bf16(aF[mi], bF[nj], acc[mi][nj]);
      __builtin_amdgcn_s_setprio(0);
      if (pf){
        if (BN == 256) asm volatile("s_waitcnt vmcnt(4)" ::: "memory");
        else           asm volatile("s_waitcnt vmcnt(3)" ::: "memory");
      } else if (ks == 0){
        asm volatile("s_waitcnt vmcnt(0)" ::: "memory");
      }
      __builtin_amdgcn_s_barrier();
    }
    bufc ^= SBUF;
  }
#undef STAGE

  // ---- epilogue ----
  #pragma unroll
  for (int mi = 0; mi < 8; mi++){
    const int mrow = m0 + wv_m * 128 + mi * 16 + fg * 4;
    #pragma unroll
    for (int nj = 0; nj < NJ; nj++){
      const int ncol = n0 + wv_n * (BN / 4) + nj * 16 + fr;
      const float bv = bias[ncol];
      #pragma unroll
      for (int r2 = 0; r2 < 4; r2++){
        const size_t idx = (size_t)(mrow + r2) * N + ncol;
        float v = acc[mi][nj][r2] + bv;
        if (EPI == EPI_RESF32){
          ((float*)outp)[idx] = v + res[idx];
        } else if (EPI == EPI_GELU){
          const float tt = tanhf(0.7978845608028654f * (v + 0.044715f * v * v * v));
          ((unsigned short*)outp)[idx] = f2bf(0.5f * v * (1.0f + tt));
        } else {
          ((unsigned short*)outp)[idx] = f2bf(v);
        }
      }
    }
  }
}

// ===== causal flash attention (unchanged) =====
template<bool MASK>
__device__ __forceinline__ void attn_tile(
    const unsigned short* __restrict__ Kc, const unsigned short* __restrict__ Vc,
    const short8 (&qf)[4], int kvbase, int qg, int l31, int hi,
    float& m_r, float& lsum, f32x16& Oa, f32x16& Ob)
{
  f32x16 Sa = zero16();
  f32x16 Sb = zero16();
  const int xb = l31 & 7;
  #pragma unroll
  for (int kk = 0; kk < 4; kk++){
    const int x = kk * 2 + hi;
    const short8 k0 = *(const short8*)((const char*)Kc + l31 * 128 + ((x ^ xb) << 4));
    const short8 k1 = *(const short8*)((const char*)Kc + (l31 + 32) * 128 + ((x ^ xb) << 4));
    Sa = mfma32(k0, qf[kk], Sa);
    Sb = mfma32(k1, qf[kk], Sb);
  }
  if (MASK){
    #pragma unroll
    for (int r = 0; r < 16; r++){
      const int kva = kvbase + (r & 3) + 8 * (r >> 2) + 4 * hi;
      Sa[r] = (kva > qg)      ? -1e30f : Sa[r];
      Sb[r] = (kva + 32 > qg) ? -1e30f : Sb[r];
    }
  }
  float tmax = Sa[0];
  #pragma unroll
  for (int r = 1; r < 16; r++) tmax = fmaxf(tmax, Sa[r]);
  #pragma unroll
  for (int r = 0; r < 16; r++) tmax = fmaxf(tmax, Sb[r]);
  tmax = fmaxf(tmax, __shfl_xor(tmax, 32));
  if (__any(tmax > m_r + 10.0f)){
    const float mn = fmaxf(m_r, tmax);
    const float sc = exp2g(m_r - mn);
    m_r = mn;
    lsum *= sc;
    #pragma unroll
    for (int r = 0; r < 16; r++){ Oa[r] *= sc; Ob[r] *= sc; }
  }
  float rs = 0.0f;
  #pragma unroll
  for (int r = 0; r < 16; r++){
    Sa[r] = exp2g(Sa[r] - m_r); rs += Sa[r];
    Sb[r] = exp2g(Sb[r] - m_r); rs += Sb[r];
  }
  rs += __shfl_xor(rs, 32);
  lsum += rs;

  short8 pf[4];
  {
    uint32 a0 = cvtpk_bf(Sa[0], Sa[1]),   b0 = cvtpk_bf(Sa[4], Sa[5]);
    uint32 a1 = cvtpk_bf(Sa[2], Sa[3]),   b1 = cvtpk_bf(Sa[6], Sa[7]);
    plswap(a0, b0); plswap(a1, b1);
    uint32 a2 = cvtpk_bf(Sa[8], Sa[9]),   b2 = cvtpk_bf(Sa[12], Sa[13]);
    uint32 a3 = cvtpk_bf(Sa[10], Sa[11]), b3 = cvtpk_bf(Sa[14], Sa[15]);
    plswap(a2, b2); plswap(a3, b3);
    union { uint32 u[4]; short8 s; } m0, m1;
    m0.u[0] = a0; m0.u[1] = a1; m0.u[2] = b0; m0.u[3] = b1;
    m1.u[0] = a2; m1.u[1] = a3; m1.u[2] = b2; m1.u[3] = b3;
    pf[0] = m0.s; pf[1] = m1.s;
  }
  {
    uint32 a0 = cvtpk_bf(Sb[0], Sb[1]),   b0 = cvtpk_bf(Sb[4], Sb[5]);
    uint32 a1 = cvtpk_bf(Sb[2], Sb[3]),   b1 = cvtpk_bf(Sb[6], Sb[7]);
    plswap(a0, b0); plswap(a1, b1);
    uint32 a2 = cvtpk_bf(Sb[8], Sb[9]),   b2 = cvtpk_bf(Sb[12], Sb[13]);
    uint32 a3 = cvtpk_bf(Sb[10], Sb[11]), b3 = cvtpk_bf(Sb[14], Sb[15]);
    plswap(a2, b2); plswap(a3, b3);
    union { uint32 u[4]; short8 s; } m0, m1;
    m0.u[0] = a0; m0.u[1] = a1; m0.u[2] = b0; m0.u[3] = b1;
    m1.u[0] = a2; m1.u[1] = a3; m1.u[2] = b2; m1.u[3] = b3;
    pf[2] = m0.s; pf[3] = m1.s;
  }
  #pragma unroll
  for (int kk = 0; kk < 4; kk++){
    const int x = kk * 2 + hi;
    const short8 v0 = *(const short8*)((const char*)Vc + l31 * 128 + ((x ^ xb) << 4));
    const short8 v1 = *(const short8*)((const char*)Vc + (l31 + 32) * 128 + ((x ^ xb) << 4));
    Oa = mfma32(v0, pf[kk], Oa);
    Ob = mfma32(v1, pf[kk], Ob);
  }
}

__global__ __launch_bounds__(256) void attn_kernel(
    const unsigned short* __restrict__ qkv,
    const unsigned short* __restrict__ vt,
    unsigned short* __restrict__ y)
{
  __shared__ __align__(16) unsigned short Klds[2][4096];
  __shared__ __align__(16) unsigned short Vlds[2][4096];
  const int bid = blockIdx.x;
  const int bh = bid & 63;
  const int qb_i = bid >> 6;
  const int b = bh >> 4, h = bh & 15;
  const int qb0 = qb_i * 128;
  const int tid = threadIdx.x;
  const int w = tid >> 6;
  const int lane = tid & 63;
  const int l31 = lane & 31;
  const int hi = lane >> 5;

  const int qrow_g = b * 2048 + qb0 + w * 32 + l31;
  const unsigned short* qp = qkv + (size_t)qrow_g * 3072 + h * 64;
  short8 qf[4];
  #pragma unroll
  for (int kk = 0; kk < 4; kk++){
    short8 raw = *(const short8*)&qp[kk * 16 + hi * 8];
    #pragma unroll
    for (int j = 0; j < 8; j++)
      qf[kk][j] = (short)f2bf(bf2f((unsigned short)raw[j]) * 0.18033688011112042f);
  }

  const int sr = tid >> 3;
  const int ce = ((tid & 7) ^ (sr & 7)) * 8;
  const unsigned short* kb = qkv + (size_t)(b * 2048) * 3072 + 1024 + h * 64;
  const unsigned short* vb = vt + (size_t)bh * 64 * 2048;

  f32x16 Oa = zero16(), Ob = zero16();
  float m_r = -1e30f, lsum = 0.0f;
  const int qmin = qb0 + w * 32;
  const int qmax = qmin + 31;
  const int qg = qmin + l31;
  const int nkv = (qb0 >> 6) + 2;

#define STAGE(t, bb) do { \
    const size_t kro = (size_t)((t) * 64 + sr) * 3072; \
    gload_lds16(kb + kro + ce,                         (char*)&Klds[bb][0] + tid * 16); \
    gload_lds16(kb + kro + (size_t)32 * 3072 + ce,     (char*)&Klds[bb][0] + 4096 + tid * 16); \
    gload_lds16(vb + (size_t)sr * 2048 + (t) * 64 + ce,        (char*)&Vlds[bb][0] + tid * 16); \
    gload_lds16(vb + (size_t)(sr + 32) * 2048 + (t) * 64 + ce, (char*)&Vlds[bb][0] + 4096 + tid * 16); \
  } while (0)

  STAGE(0, 0);
  __syncthreads();
  int cur = 0;
  for (int kvt = 0; kvt < nkv; kvt++){
    if (kvt + 1 < nkv){
      if (cur) STAGE(kvt + 1, 0); else STAGE(kvt + 1, 1);
    }
    if (kvt * 64 <= qmax){
      if (kvt * 64 + 63 <= qmin)
        attn_tile<false>(Klds[cur], Vlds[cur], qf, kvt * 64, qg, l31, hi, m_r, lsum, Oa, Ob);
      else
        attn_tile<true >(Klds[cur], Vlds[cur], qf, kvt * 64, qg, l31, hi, m_r, lsum, Oa, Ob);
    }
    __syncthreads();
    cur ^= 1;
  }
#undef STAGE

  const float inv = 1.0f / lsum;
  unsigned short* yp = y + (size_t)qrow_g * 1024 + h * 64;
  #pragma unroll
  for (int c2 = 0; c2 < 4; c2++){
    uint2v da, db;
    da.x = cvtpk_bf(Oa[4 * c2 + 0] * inv, Oa[4 * c2 + 1] * inv);
    da.y = cvtpk_bf(Oa[4 * c2 + 2] * inv, Oa[4 * c2 + 3] * inv);
    *(uint2v*)&yp[8 * c2 + 4 * hi] = da;
    db.x = cvtpk_bf(Ob[4 * c2 + 0] * inv, Ob[4 * c2 + 1] * inv);
    db.y = cvtpk_bf(Ob[4 * c2 + 2] * inv, Ob[4 * c2 + 3] * inv);
    *(uint2v*)&yp[32 + 8 * c2 + 4 * hi] = db;
  }
}

// ===== launch =====
extern "C" void kernel_launch(void* const* d_in, const int* in_sizes, int n_in,
                              void* d_out, int out_size, void* d_ws, size_t ws_size,
                              hipStream_t stream)
{
  const float* x      = (const float*)d_in[0];
  const float* ln1_w  = (const float*)d_in[1];
  const float* ln1_b  = (const float*)d_in[2];
  const float* w_attn = (const float*)d_in[3];
  const float* b_attn = (const float*)d_in[4];
  const float* w_proj = (const float*)d_in[5];
  const float* b_proj = (const float*)d_in[6];
  const float* ln2_w  = (const float*)d_in[7];
  const float* ln2_b  = (const float*)d_in[8];
  const float* w_fc   = (const float*)d_in[9];
  const float* b_fc   = (const float*)d_in[10];
  const float* w_fc2  = (const float*)d_in[11];
  const float* b_fc2  = (const float*)d_in[12];

  char* ws = (char*)d_ws;
  unsigned short* wbT_attn = (unsigned short*)(ws + 0);          //  [3072][1024]
  unsigned short* wbT_proj = (unsigned short*)(ws + 6291456);    //  [1024][1024]
  unsigned short* wbT_fc   = (unsigned short*)(ws + 8388608);    //  [4096][1024]
  unsigned short* wbT_fc2  = (unsigned short*)(ws + 16777216);   //  [1024][4096]
  unsigned short* h_bf     = (unsigned short*)(ws + 25165824);   //  [8192][1024]
  unsigned short* qkv_bf   = (unsigned short*)(ws + 41943040);   //  [8192][3072]
  unsigned short* vt_bf    = (unsigned short*)(ws + 92274688);   //  [64][64][2048]
  unsigned short* g_bf     = (unsigned short*)(ws + 41943040);   //  alias qkv+vt: [8192][4096]
  unsigned short* y_bf     = (unsigned short*)(ws + 109051904);  //  [8192][1024]
  float*          x1       = (float*)(ws + 125829120);           //  [8192][1024]
  float* outf = (float*)d_out;

  wtrans_kernel<<<dim3(3072/32, 1024/32), 256, 0, stream>>>(w_attn, wbT_attn, 1024, 3072);
  wtrans_kernel<<<dim3(1024/32, 1024/32), 256, 0, stream>>>(w_proj, wbT_proj, 1024, 1024);
  wtrans_kernel<<<dim3(4096/32, 1024/32), 256, 0, stream>>>(w_fc,   wbT_fc,   1024, 4096);
  wtrans_kernel<<<dim3(1024/32, 4096/32), 256, 0, stream>>>(w_fc2,  wbT_fc2,  4096, 1024);

  // LN1: x -> h_bf
  ln_kernel<<<8192, 256, 0, stream>>>(x, ln1_w, ln1_b, h_bf);
  // qkv = h @ w_attn + b_attn   (grid = 32 x 12 = 384)
  gemm3_kernel<EPI_BF16, 256><<<384, 512, 0, stream>>>(
      h_bf, wbT_attn, b_attn, nullptr, qkv_bf, 8192, 3072, 1024);
  // V transpose for PV operand
  vtrans_kernel<<<dim3(64, 2, 64), 256, 0, stream>>>(qkv_bf, vt_bf);
  // causal flash attention -> y_bf
  attn_kernel<<<1024, 256, 0, stream>>>(qkv_bf, vt_bf, y_bf);
  // x1 = x + y @ w_proj + b_proj   (grid = 32 x 8 = 256)
  gemm3_kernel<EPI_RESF32, 128><<<256, 512, 0, stream>>>(
      y_bf, wbT_proj, b_proj, x, x1, 8192, 1024, 1024);
  // LN2: x1 -> h_bf
  ln_kernel<<<8192, 256, 0, stream>>>(x1, ln2_w, ln2_b, h_bf);
  // g = gelu(h2 @ w_fc + b_fc)   (grid = 32 x 16 = 512)
  gemm3_kernel<EPI_GELU, 256><<<512, 512, 0, stream>>>(
      h_bf, wbT_fc, b_fc, nullptr, g_bf, 8192, 4096, 1024);
  // out = x1 + g @ w_fc2 + b_fc2   (grid = 32 x 8 = 256)
  gemm3_kernel<EPI_RESF32, 128><<<256, 512, 0, stream>>>(
      g_bf, wbT_fc2, b_fc2, x1, outf, 8192, 1024, 4096);
}

// Round 6
// 392.495 us; speedup vs baseline: 1.7517x; 1.0035x over previous
//
#include <hip/hip_runtime.h>

// ===== types =====
typedef __attribute__((ext_vector_type(8))) short short8;       // 8 x bf16 bits
typedef __attribute__((ext_vector_type(8))) unsigned short ushort8;
typedef __attribute__((ext_vector_type(4))) float f32x4;
typedef __attribute__((ext_vector_type(16))) float f32x16;
typedef __attribute__((ext_vector_type(2))) unsigned int uint2v;
typedef unsigned int uint32;

__device__ __forceinline__ unsigned short f2bf(float f){
  union { float f; unsigned int u; } x; x.f = f;
  unsigned int u = x.u;
  u += 0x7fffu + ((u >> 16) & 1u);   // RNE
  return (unsigned short)(u >> 16);
}
__device__ __forceinline__ float bf2f(unsigned short s){
  union { float f; unsigned int u; } x; x.u = ((uint32)s) << 16; return x.f;
}

typedef __attribute__((address_space(1))) void gvoid;
typedef __attribute__((address_space(3))) void lvoid;
__device__ __forceinline__ void gload_lds16(const void* g, void* l){
  __builtin_amdgcn_global_load_lds((gvoid*)g, (lvoid*)l, 16, 0, 0);
}

__device__ __forceinline__ f32x4 mfma_bf16(short8 a, short8 b, f32x4 c){
  return __builtin_amdgcn_mfma_f32_16x16x32_bf16(a, b, c, 0, 0, 0);
}
__device__ __forceinline__ f32x16 mfma32(short8 a, short8 b, f32x16 c){
  return __builtin_amdgcn_mfma_f32_32x32x16_bf16(a, b, c, 0, 0, 0);
}

__device__ __forceinline__ uint32 cvtpk_bf(float lo, float hi){
  uint32 r;
  asm("v_cvt_pk_bf16_f32 %0, %1, %2" : "=v"(r) : "v"(lo), "v"(hi));
  return r;
}
__device__ __forceinline__ void plswap(uint32& a, uint32& b){
  auto r = __builtin_amdgcn_permlane32_swap(a, b, false, false);
  a = r[0]; b = r[1];
}

#if __has_builtin(__builtin_amdgcn_exp2f)
__device__ __forceinline__ float exp2g(float x){ return __builtin_amdgcn_exp2f(x); }
#else
__device__ __forceinline__ float exp2g(float x){ return exp2f(x); }
#endif

__device__ __forceinline__ f32x16 zero16(){
  f32x16 z;
  #pragma unroll
  for (int i = 0; i < 16; i++) z[i] = 0.0f;
  return z;
}

// ===== weight transpose + fp32->bf16: w[K][N] -> wt[N][K] =====
__global__ __launch_bounds__(256) void wtrans_kernel(
    const float* __restrict__ w, unsigned short* __restrict__ wt, int K, int N)
{
  __shared__ float tile[32][33];
  const int n0 = blockIdx.x * 32;
  const int k0 = blockIdx.y * 32;
  const int t = threadIdx.x;
  #pragma unroll
  for (int i = 0; i < 4; i++){
    const int e = t + i * 256;
    const int r = e >> 5, c = e & 31;
    tile[r][c] = w[(size_t)(k0 + r) * N + n0 + c];
  }
  __syncthreads();
  #pragma unroll
  for (int i = 0; i < 4; i++){
    const int e = t + i * 256;
    const int r = e >> 5, c = e & 31;   // r = n-local, c = k-local
    wt[(size_t)(n0 + r) * K + k0 + c] = f2bf(tile[c][r]);
  }
}

// ===== V transpose: qkv[8192][3072] (v at col 2048+h*64) -> vt[bh][64][2048] bf16 =====
__global__ __launch_bounds__(256) void vtrans_kernel(
    const unsigned short* __restrict__ qkv, unsigned short* __restrict__ vt)
{
  __shared__ unsigned short tile[32][33];
  const int bh = blockIdx.z;
  const int b = bh >> 4, h = bh & 15;
  const int t0 = blockIdx.x * 32;
  const int f0 = blockIdx.y * 32;
  const int t = threadIdx.x;
  #pragma unroll
  for (int i = 0; i < 4; i++){
    const int e = t + i * 256;
    const int r = e >> 5, c = e & 31;   // r = t-local, c = feat-local
    tile[r][c] = qkv[(size_t)(b * 2048 + t0 + r) * 3072 + 2048 + h * 64 + f0 + c];
  }
  __syncthreads();
  #pragma unroll
  for (int i = 0; i < 4; i++){
    const int e = t + i * 256;
    const int r = e >> 5, c = e & 31;   // r = feat-local, c = t-local
    vt[((size_t)bh * 64 + f0 + r) * 2048 + t0 + c] = tile[c][r];
  }
}

// ===== LayerNorm fp32 -> bf16 (row = 1024) =====
__global__ __launch_bounds__(256) void ln_kernel(
    const float* __restrict__ x, const float* __restrict__ w, const float* __restrict__ b,
    unsigned short* __restrict__ out)
{
  const int row = blockIdx.x;
  const int t = threadIdx.x;
  const float4 v = ((const float4*)(x + (size_t)row * 1024))[t];
  float s  = v.x + v.y + v.z + v.w;
  float s2 = v.x * v.x + v.y * v.y + v.z * v.z + v.w * v.w;
  #pragma unroll
  for (int off = 32; off > 0; off >>= 1){
    s  += __shfl_xor(s, off);
    s2 += __shfl_xor(s2, off);
  }
  __shared__ float ps[8];
  const int wid = t >> 6;
  if ((t & 63) == 0){ ps[wid] = s; ps[4 + wid] = s2; }
  __syncthreads();
  s  = ps[0] + ps[1] + ps[2] + ps[3];
  s2 = ps[4] + ps[5] + ps[6] + ps[7];
  const float mu  = s * (1.0f / 1024.0f);
  const float var = s2 * (1.0f / 1024.0f) - mu * mu;
  const float rs  = rsqrtf(var + 1e-5f);
  const float4 wv = ((const float4*)w)[t];
  const float4 bv = ((const float4*)b)[t];
  ushort4 ov;
  ov.x = f2bf((v.x - mu) * rs * wv.x + bv.x);
  ov.y = f2bf((v.y - mu) * rs * wv.y + bv.y);
  ov.z = f2bf((v.z - mu) * rs * wv.z + bv.z);
  ov.w = f2bf((v.w - mu) * rs * wv.w + bv.w);
  ((ushort4*)(out + (size_t)row * 1024))[t] = ov;
}

// ===== GEMM v5: m201 phase granularity =====================================
// C[M][N] = A[M][K](bf16) @ BT[N][K]^T + bias (+res / gelu).
// BM=256, 512 thr = 8 waves. BN=256: waves 2Mx4N, per-wave 128x64, MI=8.
// BN=128: waves 4Mx2N, per-wave 64x64, MI=4. NJ=4 both.
// Ring-4 of K=32 slices (slot = A 16KB + B 8/16KB; 96/128 KB total).
// Stage slice s+3 while computing slice s; steady-state vmcnt(2*LPS)
// (8 for BN=256, 6 for BN=128) - never drains to 0 mid-loop; tail LPS->0.
// Per slice: SP=MI/4 sub-phases, each EXACTLY the m201 phase shape:
//   {4 aF ds_reads (+4 bF on sp0) || 2-3 stage loads -> s_barrier ->
//    lgkmcnt(0)+sched_barrier -> setprio(1) -> 16 MFMA -> setprio(0) ->
//    [vmcnt at slice end] -> s_barrier}
// Fine 16-MFMA phases with alternating 8/4-read drains are what lets the
// 2 waves/SIMD slip so LDS drain hides under MFMA (R3-R5's 32-MFMA/12-read
// phases serialized the pipes at ~26% MfmaUtil).
// Swizzle: 16B slot c ^ ((row>>1)&3), inverse-swizzled global source.
#define EPI_BF16   0
#define EPI_RESF32 1
#define EPI_GELU   2

template<int EPI, int BN>
__global__ __launch_bounds__(512, 2) void gemm4_kernel(
    const unsigned short* __restrict__ A,
    const unsigned short* __restrict__ BT,
    const float* __restrict__ bias,
    const float* __restrict__ res,
    void* __restrict__ outp,
    int M, int N, int K)
{
  constexpr int MI   = (BN == 256) ? 8 : 4;   // A frags / wave / slice
  constexpr int SP   = MI / 4;                // sub-phases / slice
  constexpr int NBL  = BN / 128;              // B stage loads / slice
  constexpr int WN   = (BN == 256) ? 4 : 2;
  constexpr int WROWS= (BN == 256) ? 128 : 64;
  constexpr int ASL  = 16384;                 // A slice bytes (256 x 32 x 2B)
  constexpr int SLOT = ASL + BN * 64;         // ring slot bytes
  __shared__ __align__(16) char lds[4 * SLOT];

  // XCD-aware bijective swizzle (nwg % 8 == 0 for all shapes used)
  const int nwg = gridDim.x;
  const int bid = blockIdx.x;
  const int wg = (bid & 7) * (nwg >> 3) + (bid >> 3);
  const int NTile = N / BN;
  const int mt = wg / NTile;
  const int nti = wg - mt * NTile;
  const int m0 = mt << 8;
  const int n0 = nti * BN;

  const int tid = threadIdx.x;
  const int lane = tid & 63;
  const int wid = tid >> 6;
  const int wv_m = wid / WN;
  const int wv_n = wid % WN;
  const int fr = lane & 15;
  const int fg = lane >> 4;

  // ---- staging geometry (slot s -> row=s>>2, c=s&3; inverse-swizzled src) --
  const unsigned short* aSrc[2];
  int aDst[2];
  #pragma unroll
  for (int l = 0; l < 2; l++){
    const int s = l * 512 + tid;
    const int r = s >> 2, c = s & 3;
    aSrc[l] = A + (size_t)(m0 + r) * K + ((c ^ ((r >> 1) & 3)) << 3);
    aDst[l] = s * 16;
  }
  const unsigned short* bSrc[NBL];
  int bDst[NBL];
  #pragma unroll
  for (int l = 0; l < NBL; l++){
    const int s = l * 512 + tid;
    const int r = s >> 2, c = s & 3;
    bSrc[l] = BT + (size_t)(n0 + r) * K + ((c ^ ((r >> 1) & 3)) << 3);
    bDst[l] = ASL + s * 16;
  }

  // ---- fragment read offsets (slice-relative, swizzled) ----
  int aOff[MI], bOff[4];
  #pragma unroll
  for (int mi = 0; mi < MI; mi++){
    const int row = wv_m * WROWS + mi * 16 + fr;
    aOff[mi] = row * 64 + ((fg ^ ((row >> 1) & 3)) << 4);
  }
  #pragma unroll
  for (int nj = 0; nj < 4; nj++){
    const int row = wv_n * 64 + nj * 16 + fr;
    bOff[nj] = ASL + row * 64 + ((fg ^ ((row >> 1) & 3)) << 4);
  }

  f32x4 acc[MI][4];
  #pragma unroll
  for (int i = 0; i < MI; i++)
    #pragma unroll
    for (int j = 0; j < 4; j++) acc[i][j] = (f32x4){0.f, 0.f, 0.f, 0.f};

#define STAGE_A(sl, slot) do { \
    gload_lds16(aSrc[0] + (size_t)(sl) * 32, lds + (slot) + aDst[0]); \
    gload_lds16(aSrc[1] + (size_t)(sl) * 32, lds + (slot) + aDst[1]); \
  } while (0)
#define STAGE_B(sl, slot) do { \
    gload_lds16(bSrc[0] + (size_t)(sl) * 32, lds + (slot) + bDst[0]); \
    if (NBL == 2) gload_lds16(bSrc[1] + (size_t)(sl) * 32, lds + (slot) + bDst[1]); \
  } while (0)

  const int NS = K >> 5;   // K=32 slices (>=32 for all our shapes)

  // prologue: stage slices 0,1,2 into ring slots 0,1,2
  STAGE_A(0, 0);        STAGE_B(0, 0);
  STAGE_A(1, SLOT);     STAGE_B(1, SLOT);
  STAGE_A(2, 2 * SLOT); STAGE_B(2, 2 * SLOT);
  if (BN == 256) asm volatile("s_waitcnt vmcnt(8)" ::: "memory");
  else           asm volatile("s_waitcnt vmcnt(6)" ::: "memory");
  __builtin_amdgcn_s_barrier();

  for (int s = 0; s < NS; s++){
    const int ss = (s & 3) * SLOT;
    const int sg = ((s + 3) & 3) * SLOT;
    const bool pf = (s + 3 < NS);
    short8 bF[4];
    #pragma unroll
    for (int sp = 0; sp < SP; sp++){
      short8 aF[4];
      #pragma unroll
      for (int i = 0; i < 4; i++)
        aF[i] = *(const short8*)(lds + ss + aOff[sp * 4 + i]);
      if (sp == 0){
        #pragma unroll
        for (int nj = 0; nj < 4; nj++)
          bF[nj] = *(const short8*)(lds + ss + bOff[nj]);
      }
      if (pf){
        if (SP == 2){
          if (sp == 0) STAGE_A(s + 3, sg);
          else         STAGE_B(s + 3, sg);
        } else {
          STAGE_A(s + 3, sg);
          STAGE_B(s + 3, sg);
        }
      }
      __builtin_amdgcn_s_barrier();
      asm volatile("s_waitcnt lgkmcnt(0)" ::: "memory");
      __builtin_amdgcn_sched_barrier(0);
      __builtin_amdgcn_s_setprio(1);
      #pragma unroll
      for (int i = 0; i < 4; i++)
        #pragma unroll
        for (int nj = 0; nj < 4; nj++)
          acc[sp * 4 + i][nj] = mfma_bf16(aF[i], bF[nj], acc[sp * 4 + i][nj]);
      __builtin_amdgcn_s_setprio(0);
      if (sp == SP - 1){
        if (s + 3 < NS){
          if (BN == 256) asm volatile("s_waitcnt vmcnt(8)" ::: "memory");
          else           asm volatile("s_waitcnt vmcnt(6)" ::: "memory");
        } else if (s + 2 < NS){
          if (BN == 256) asm volatile("s_waitcnt vmcnt(4)" ::: "memory");
          else           asm volatile("s_waitcnt vmcnt(3)" ::: "memory");
        } else if (s + 1 < NS){
          asm volatile("s_waitcnt vmcnt(0)" ::: "memory");
        }
      }
      __builtin_amdgcn_s_barrier();
    }
  }
#undef STAGE_A
#undef STAGE_B

  // ---- epilogue ----
  #pragma unroll
  for (int mi = 0; mi < MI; mi++){
    const int mrow = m0 + wv_m * WROWS + mi * 16 + fg * 4;
    #pragma unroll
    for (int nj = 0; nj < 4; nj++){
      const int ncol = n0 + wv_n * 64 + nj * 16 + fr;
      const float bv = bias[ncol];
      #pragma unroll
      for (int r2 = 0; r2 < 4; r2++){
        const size_t idx = (size_t)(mrow + r2) * N + ncol;
        float v = acc[mi][nj][r2] + bv;
        if (EPI == EPI_RESF32){
          ((float*)outp)[idx] = v + res[idx];
        } else if (EPI == EPI_GELU){
          const float tt = tanhf(0.7978845608028654f * (v + 0.044715f * v * v * v));
          ((unsigned short*)outp)[idx] = f2bf(0.5f * v * (1.0f + tt));
        } else {
          ((unsigned short*)outp)[idx] = f2bf(v);
        }
      }
    }
  }
}

// ===== causal flash attention (unchanged) =====
template<bool MASK>
__device__ __forceinline__ void attn_tile(
    const unsigned short* __restrict__ Kc, const unsigned short* __restrict__ Vc,
    const short8 (&qf)[4], int kvbase, int qg, int l31, int hi,
    float& m_r, float& lsum, f32x16& Oa, f32x16& Ob)
{
  f32x16 Sa = zero16();
  f32x16 Sb = zero16();
  const int xb = l31 & 7;
  #pragma unroll
  for (int kk = 0; kk < 4; kk++){
    const int x = kk * 2 + hi;
    const short8 k0 = *(const short8*)((const char*)Kc + l31 * 128 + ((x ^ xb) << 4));
    const short8 k1 = *(const short8*)((const char*)Kc + (l31 + 32) * 128 + ((x ^ xb) << 4));
    Sa = mfma32(k0, qf[kk], Sa);
    Sb = mfma32(k1, qf[kk], Sb);
  }
  if (MASK){
    #pragma unroll
    for (int r = 0; r < 16; r++){
      const int kva = kvbase + (r & 3) + 8 * (r >> 2) + 4 * hi;
      Sa[r] = (kva > qg)      ? -1e30f : Sa[r];
      Sb[r] = (kva + 32 > qg) ? -1e30f : Sb[r];
    }
  }
  float tmax = Sa[0];
  #pragma unroll
  for (int r = 1; r < 16; r++) tmax = fmaxf(tmax, Sa[r]);
  #pragma unroll
  for (int r = 0; r < 16; r++) tmax = fmaxf(tmax, Sb[r]);
  tmax = fmaxf(tmax, __shfl_xor(tmax, 32));
  if (__any(tmax > m_r + 10.0f)){
    const float mn = fmaxf(m_r, tmax);
    const float sc = exp2g(m_r - mn);
    m_r = mn;
    lsum *= sc;
    #pragma unroll
    for (int r = 0; r < 16; r++){ Oa[r] *= sc; Ob[r] *= sc; }
  }
  float rs = 0.0f;
  #pragma unroll
  for (int r = 0; r < 16; r++){
    Sa[r] = exp2g(Sa[r] - m_r); rs += Sa[r];
    Sb[r] = exp2g(Sb[r] - m_r); rs += Sb[r];
  }
  rs += __shfl_xor(rs, 32);
  lsum += rs;

  short8 pf[4];
  {
    uint32 a0 = cvtpk_bf(Sa[0], Sa[1]),   b0 = cvtpk_bf(Sa[4], Sa[5]);
    uint32 a1 = cvtpk_bf(Sa[2], Sa[3]),   b1 = cvtpk_bf(Sa[6], Sa[7]);
    plswap(a0, b0); plswap(a1, b1);
    uint32 a2 = cvtpk_bf(Sa[8], Sa[9]),   b2 = cvtpk_bf(Sa[12], Sa[13]);
    uint32 a3 = cvtpk_bf(Sa[10], Sa[11]), b3 = cvtpk_bf(Sa[14], Sa[15]);
    plswap(a2, b2); plswap(a3, b3);
    union { uint32 u[4]; short8 s; } m0, m1;
    m0.u[0] = a0; m0.u[1] = a1; m0.u[2] = b0; m0.u[3] = b1;
    m1.u[0] = a2; m1.u[1] = a3; m1.u[2] = b2; m1.u[3] = b3;
    pf[0] = m0.s; pf[1] = m1.s;
  }
  {
    uint32 a0 = cvtpk_bf(Sb[0], Sb[1]),   b0 = cvtpk_bf(Sb[4], Sb[5]);
    uint32 a1 = cvtpk_bf(Sb[2], Sb[3]),   b1 = cvtpk_bf(Sb[6], Sb[7]);
    plswap(a0, b0); plswap(a1, b1);
    uint32 a2 = cvtpk_bf(Sb[8], Sb[9]),   b2 = cvtpk_bf(Sb[12], Sb[13]);
    uint32 a3 = cvtpk_bf(Sb[10], Sb[11]), b3 = cvtpk_bf(Sb[14], Sb[15]);
    plswap(a2, b2); plswap(a3, b3);
    union { uint32 u[4]; short8 s; } m0, m1;
    m0.u[0] = a0; m0.u[1] = a1; m0.u[2] = b0; m0.u[3] = b1;
    m1.u[0] = a2; m1.u[1] = a3; m1.u[2] = b2; m1.u[3] = b3;
    pf[2] = m0.s; pf[3] = m1.s;
  }
  #pragma unroll
  for (int kk = 0; kk < 4; kk++){
    const int x = kk * 2 + hi;
    const short8 v0 = *(const short8*)((const char*)Vc + l31 * 128 + ((x ^ xb) << 4));
    const short8 v1 = *(const short8*)((const char*)Vc + (l31 + 32) * 128 + ((x ^ xb) << 4));
    Oa = mfma32(v0, pf[kk], Oa);
    Ob = mfma32(v1, pf[kk], Ob);
  }
}

__global__ __launch_bounds__(256) void attn_kernel(
    const unsigned short* __restrict__ qkv,
    const unsigned short* __restrict__ vt,
    unsigned short* __restrict__ y)
{
  __shared__ __align__(16) unsigned short Klds[2][4096];
  __shared__ __align__(16) unsigned short Vlds[2][4096];
  const int bid = blockIdx.x;
  const int bh = bid & 63;
  const int qb_i = bid >> 6;
  const int b = bh >> 4, h = bh & 15;
  const int qb0 = qb_i * 128;
  const int tid = threadIdx.x;
  const int w = tid >> 6;
  const int lane = tid & 63;
  const int l31 = lane & 31;
  const int hi = lane >> 5;

  const int qrow_g = b * 2048 + qb0 + w * 32 + l31;
  const unsigned short* qp = qkv + (size_t)qrow_g * 3072 + h * 64;
  short8 qf[4];
  #pragma unroll
  for (int kk = 0; kk < 4; kk++){
    short8 raw = *(const short8*)&qp[kk * 16 + hi * 8];
    #pragma unroll
    for (int j = 0; j < 8; j++)
      qf[kk][j] = (short)f2bf(bf2f((unsigned short)raw[j]) * 0.18033688011112042f);
  }

  const int sr = tid >> 3;
  const int ce = ((tid & 7) ^ (sr & 7)) * 8;
  const unsigned short* kb = qkv + (size_t)(b * 2048) * 3072 + 1024 + h * 64;
  const unsigned short* vb = vt + (size_t)bh * 64 * 2048;

  f32x16 Oa = zero16(), Ob = zero16();
  float m_r = -1e30f, lsum = 0.0f;
  const int qmin = qb0 + w * 32;
  const int qmax = qmin + 31;
  const int qg = qmin + l31;
  const int nkv = (qb0 >> 6) + 2;

#define STAGE(t, bb) do { \
    const size_t kro = (size_t)((t) * 64 + sr) * 3072; \
    gload_lds16(kb + kro + ce,                         (char*)&Klds[bb][0] + tid * 16); \
    gload_lds16(kb + kro + (size_t)32 * 3072 + ce,     (char*)&Klds[bb][0] + 4096 + tid * 16); \
    gload_lds16(vb + (size_t)sr * 2048 + (t) * 64 + ce,        (char*)&Vlds[bb][0] + tid * 16); \
    gload_lds16(vb + (size_t)(sr + 32) * 2048 + (t) * 64 + ce, (char*)&Vlds[bb][0] + 4096 + tid * 16); \
  } while (0)

  STAGE(0, 0);
  __syncthreads();
  int cur = 0;
  for (int kvt = 0; kvt < nkv; kvt++){
    if (kvt + 1 < nkv){
      if (cur) STAGE(kvt + 1, 0); else STAGE(kvt + 1, 1);
    }
    if (kvt * 64 <= qmax){
      if (kvt * 64 + 63 <= qmin)
        attn_tile<false>(Klds[cur], Vlds[cur], qf, kvt * 64, qg, l31, hi, m_r, lsum, Oa, Ob);
      else
        attn_tile<true >(Klds[cur], Vlds[cur], qf, kvt * 64, qg, l31, hi, m_r, lsum, Oa, Ob);
    }
    __syncthreads();
    cur ^= 1;
  }
#undef STAGE

  const float inv = 1.0f / lsum;
  unsigned short* yp = y + (size_t)qrow_g * 1024 + h * 64;
  #pragma unroll
  for (int c2 = 0; c2 < 4; c2++){
    uint2v da, db;
    da.x = cvtpk_bf(Oa[4 * c2 + 0] * inv, Oa[4 * c2 + 1] * inv);
    da.y = cvtpk_bf(Oa[4 * c2 + 2] * inv, Oa[4 * c2 + 3] * inv);
    *(uint2v*)&yp[8 * c2 + 4 * hi] = da;
    db.x = cvtpk_bf(Ob[4 * c2 + 0] * inv, Ob[4 * c2 + 1] * inv);
    db.y = cvtpk_bf(Ob[4 * c2 + 2] * inv, Ob[4 * c2 + 3] * inv);
    *(uint2v*)&yp[32 + 8 * c2 + 4 * hi] = db;
  }
}

// ===== launch =====
extern "C" void kernel_launch(void* const* d_in, const int* in_sizes, int n_in,
                              void* d_out, int out_size, void* d_ws, size_t ws_size,
                              hipStream_t stream)
{
  const float* x      = (const float*)d_in[0];
  const float* ln1_w  = (const float*)d_in[1];
  const float* ln1_b  = (const float*)d_in[2];
  const float* w_attn = (const float*)d_in[3];
  const float* b_attn = (const float*)d_in[4];
  const float* w_proj = (const float*)d_in[5];
  const float* b_proj = (const float*)d_in[6];
  const float* ln2_w  = (const float*)d_in[7];
  const float* ln2_b  = (const float*)d_in[8];
  const float* w_fc   = (const float*)d_in[9];
  const float* b_fc   = (const float*)d_in[10];
  const float* w_fc2  = (const float*)d_in[11];
  const float* b_fc2  = (const float*)d_in[12];

  char* ws = (char*)d_ws;
  unsigned short* wbT_attn = (unsigned short*)(ws + 0);          //  [3072][1024]
  unsigned short* wbT_proj = (unsigned short*)(ws + 6291456);    //  [1024][1024]
  unsigned short* wbT_fc   = (unsigned short*)(ws + 8388608);    //  [4096][1024]
  unsigned short* wbT_fc2  = (unsigned short*)(ws + 16777216);   //  [1024][4096]
  unsigned short* h_bf     = (unsigned short*)(ws + 25165824);   //  [8192][1024]
  unsigned short* qkv_bf   = (unsigned short*)(ws + 41943040);   //  [8192][3072]
  unsigned short* vt_bf    = (unsigned short*)(ws + 92274688);   //  [64][64][2048]
  unsigned short* g_bf     = (unsigned short*)(ws + 41943040);   //  alias qkv+vt: [8192][4096]
  unsigned short* y_bf     = (unsigned short*)(ws + 109051904);  //  [8192][1024]
  float*          x1       = (float*)(ws + 125829120);           //  [8192][1024]
  float* outf = (float*)d_out;

  wtrans_kernel<<<dim3(3072/32, 1024/32), 256, 0, stream>>>(w_attn, wbT_attn, 1024, 3072);
  wtrans_kernel<<<dim3(1024/32, 1024/32), 256, 0, stream>>>(w_proj, wbT_proj, 1024, 1024);
  wtrans_kernel<<<dim3(4096/32, 1024/32), 256, 0, stream>>>(w_fc,   wbT_fc,   1024, 4096);
  wtrans_kernel<<<dim3(1024/32, 4096/32), 256, 0, stream>>>(w_fc2,  wbT_fc2,  4096, 1024);

  // LN1: x -> h_bf
  ln_kernel<<<8192, 256, 0, stream>>>(x, ln1_w, ln1_b, h_bf);
  // qkv = h @ w_attn + b_attn   (grid = 32 x 12 = 384)
  gemm4_kernel<EPI_BF16, 256><<<384, 512, 0, stream>>>(
      h_bf, wbT_attn, b_attn, nullptr, qkv_bf, 8192, 3072, 1024);
  // V transpose for PV operand
  vtrans_kernel<<<dim3(64, 2, 64), 256, 0, stream>>>(qkv_bf, vt_bf);
  // causal flash attention -> y_bf
  attn_kernel<<<1024, 256, 0, stream>>>(qkv_bf, vt_bf, y_bf);
  // x1 = x + y @ w_proj + b_proj   (grid = 32 x 8 = 256)
  gemm4_kernel<EPI_RESF32, 128><<<256, 512, 0, stream>>>(
      y_bf, wbT_proj, b_proj, x, x1, 8192, 1024, 1024);
  // LN2: x1 -> h_bf
  ln_kernel<<<8192, 256, 0, stream>>>(x1, ln2_w, ln2_b, h_bf);
  // g = gelu(h2 @ w_fc + b_fc)   (grid = 32 x 16 = 512)
  gemm4_kernel<EPI_GELU, 256><<<512, 512, 0, stream>>>(
      h_bf, wbT_fc, b_fc, nullptr, g_bf, 8192, 4096, 1024);
  // out = x1 + g @ w_fc2 + b_fc2   (grid = 32 x 8 = 256)
  gemm4_kernel<EPI_RESF32, 128><<<256, 512, 0, stream>>>(
      g_bf, wbT_fc2, b_fc2, x1, outf, 8192, 1024, 4096);
}

// Round 7
// 359.275 us; speedup vs baseline: 1.9136x; 1.0925x over previous
//
#include <hip/hip_runtime.h>

// ===== types =====
typedef __attribute__((ext_vector_type(8))) short short8;       // 8 x bf16 bits
typedef __attribute__((ext_vector_type(8))) unsigned short ushort8;
typedef __attribute__((ext_vector_type(4))) float f32x4;
typedef __attribute__((ext_vector_type(16))) float f32x16;
typedef __attribute__((ext_vector_type(2))) unsigned int uint2v;
typedef unsigned int uint32;

__device__ __forceinline__ unsigned short f2bf(float f){
  union { float f; unsigned int u; } x; x.f = f;
  unsigned int u = x.u;
  u += 0x7fffu + ((u >> 16) & 1u);   // RNE
  return (unsigned short)(u >> 16);
}
__device__ __forceinline__ float bf2f(unsigned short s){
  union { float f; unsigned int u; } x; x.u = ((uint32)s) << 16; return x.f;
}

typedef __attribute__((address_space(1))) void gvoid;
typedef __attribute__((address_space(3))) void lvoid;
__device__ __forceinline__ void gload_lds16(const void* g, void* l){
  __builtin_amdgcn_global_load_lds((gvoid*)g, (lvoid*)l, 16, 0, 0);
}

__device__ __forceinline__ f32x4 mfma_bf16(short8 a, short8 b, f32x4 c){
  return __builtin_amdgcn_mfma_f32_16x16x32_bf16(a, b, c, 0, 0, 0);
}
__device__ __forceinline__ f32x16 mfma32(short8 a, short8 b, f32x16 c){
  return __builtin_amdgcn_mfma_f32_32x32x16_bf16(a, b, c, 0, 0, 0);
}

__device__ __forceinline__ uint32 cvtpk_bf(float lo, float hi){
  uint32 r;
  asm("v_cvt_pk_bf16_f32 %0, %1, %2" : "=v"(r) : "v"(lo), "v"(hi));
  return r;
}
__device__ __forceinline__ void plswap(uint32& a, uint32& b){
  auto r = __builtin_amdgcn_permlane32_swap(a, b, false, false);
  a = r[0]; b = r[1];
}

#if __has_builtin(__builtin_amdgcn_exp2f)
__device__ __forceinline__ float exp2g(float x){ return __builtin_amdgcn_exp2f(x); }
#else
__device__ __forceinline__ float exp2g(float x){ return exp2f(x); }
#endif
#if __has_builtin(__builtin_amdgcn_rcpf)
__device__ __forceinline__ float rcpg(float x){ return __builtin_amdgcn_rcpf(x); }
#else
__device__ __forceinline__ float rcpg(float x){ return 1.0f / x; }
#endif

// fast gelu: v - v/(1+exp2(2*log2e * u)), u = c0*(v + 0.044715 v^3)
__device__ __forceinline__ float gelu_fast(float v){
  const float u = 0.7978845608028654f * (v + 0.044715f * v * v * v);
  const float E = exp2g(2.8853900817779268f * u);
  return v - v * rcpg(1.0f + E);
}

__device__ __forceinline__ f32x16 zero16(){
  f32x16 z;
  #pragma unroll
  for (int i = 0; i < 16; i++) z[i] = 0.0f;
  return z;
}

// ===== weight transpose + fp32->bf16: w[K][N] -> wt[N][K] =====
__global__ __launch_bounds__(256) void wtrans_kernel(
    const float* __restrict__ w, unsigned short* __restrict__ wt, int K, int N)
{
  __shared__ float tile[32][33];
  const int n0 = blockIdx.x * 32;
  const int k0 = blockIdx.y * 32;
  const int t = threadIdx.x;
  #pragma unroll
  for (int i = 0; i < 4; i++){
    const int e = t + i * 256;
    const int r = e >> 5, c = e & 31;
    tile[r][c] = w[(size_t)(k0 + r) * N + n0 + c];
  }
  __syncthreads();
  #pragma unroll
  for (int i = 0; i < 4; i++){
    const int e = t + i * 256;
    const int r = e >> 5, c = e & 31;   // r = n-local, c = k-local
    wt[(size_t)(n0 + r) * K + k0 + c] = f2bf(tile[c][r]);
  }
}

// ===== V transpose: qkv[8192][3072] (v at col 2048+h*64) -> vt[bh][64][2048] bf16 =====
__global__ __launch_bounds__(256) void vtrans_kernel(
    const unsigned short* __restrict__ qkv, unsigned short* __restrict__ vt)
{
  __shared__ unsigned short tile[32][33];
  const int bh = blockIdx.z;
  const int b = bh >> 4, h = bh & 15;
  const int t0 = blockIdx.x * 32;
  const int f0 = blockIdx.y * 32;
  const int t = threadIdx.x;
  #pragma unroll
  for (int i = 0; i < 4; i++){
    const int e = t + i * 256;
    const int r = e >> 5, c = e & 31;   // r = t-local, c = feat-local
    tile[r][c] = qkv[(size_t)(b * 2048 + t0 + r) * 3072 + 2048 + h * 64 + f0 + c];
  }
  __syncthreads();
  #pragma unroll
  for (int i = 0; i < 4; i++){
    const int e = t + i * 256;
    const int r = e >> 5, c = e & 31;   // r = feat-local, c = t-local
    vt[((size_t)bh * 64 + f0 + r) * 2048 + t0 + c] = tile[c][r];
  }
}

// ===== LayerNorm fp32 -> bf16 (row = 1024) =====
__global__ __launch_bounds__(256) void ln_kernel(
    const float* __restrict__ x, const float* __restrict__ w, const float* __restrict__ b,
    unsigned short* __restrict__ out)
{
  const int row = blockIdx.x;
  const int t = threadIdx.x;
  const float4 v = ((const float4*)(x + (size_t)row * 1024))[t];
  float s  = v.x + v.y + v.z + v.w;
  float s2 = v.x * v.x + v.y * v.y + v.z * v.z + v.w * v.w;
  #pragma unroll
  for (int off = 32; off > 0; off >>= 1){
    s  += __shfl_xor(s, off);
    s2 += __shfl_xor(s2, off);
  }
  __shared__ float ps[8];
  const int wid = t >> 6;
  if ((t & 63) == 0){ ps[wid] = s; ps[4 + wid] = s2; }
  __syncthreads();
  s  = ps[0] + ps[1] + ps[2] + ps[3];
  s2 = ps[4] + ps[5] + ps[6] + ps[7];
  const float mu  = s * (1.0f / 1024.0f);
  const float var = s2 * (1.0f / 1024.0f) - mu * mu;
  const float rs  = rsqrtf(var + 1e-5f);
  const float4 wv = ((const float4*)w)[t];
  const float4 bv = ((const float4*)b)[t];
  ushort4 ov;
  ov.x = f2bf((v.x - mu) * rs * wv.x + bv.x);
  ov.y = f2bf((v.y - mu) * rs * wv.y + bv.y);
  ov.z = f2bf((v.z - mu) * rs * wv.z + bv.z);
  ov.w = f2bf((v.w - mu) * rs * wv.w + bv.w);
  ((ushort4*)(out + (size_t)row * 1024))[t] = ov;
}

#define EPI_BF16   0
#define EPI_RESF32 1
#define EPI_GELU   2

// ===== GEMM v6 (gemm5): 2-blocks/CU TLP + best FLOP/LDS-byte geometry ======
// BM=128, BN=256, 256 thr = 4 waves (1M x 4N), per-wave 128x64 (8x4 frags,
// 42.7 FLOP per LDS byte). BK=32 ring-3 (slot = A 8KB + B 16KB = 24KB,
// 72KB total) -> 2 INDEPENDENT blocks/CU: when one block drains lgkm/barrier,
// the other block's MFMAs fill the CU (the m97 overlap mechanism, which
// 1-block/CU barrier-locked designs R3-R6 could not access; all were pinned
// at ~25% MfmaUtil regardless of schedule).
// Per slice: {12 ds_read_b128 frags; stage slice s+2 (6 gload_lds16);
// 32 MFMA compiler-interleaved; vmcnt(6) (never 0 mid-loop); barrier}.
// Swizzle: 16B slot c ^ ((row>>1)&3) -> 2-way (free), inverse-swizzled src.
template<int EPI>
__global__ __launch_bounds__(256, 2) void gemm5_kernel(
    const unsigned short* __restrict__ A,
    const unsigned short* __restrict__ BT,
    const float* __restrict__ bias,
    const float* __restrict__ res,
    void* __restrict__ outp,
    int M, int N, int K)
{
  constexpr int SLOT = 24576;   // A 8KB + B 16KB
  __shared__ __align__(16) char lds[3 * SLOT];

  // XCD-aware bijective swizzle (nwg % 8 == 0 for all shapes used)
  const int nwg = gridDim.x;
  const int bid = blockIdx.x;
  const int wg = (bid & 7) * (nwg >> 3) + (bid >> 3);
  const int NT = N >> 8;
  const int mt = wg / NT;
  const int nti = wg - mt * NT;
  const int m0 = mt << 7;
  const int n0 = nti << 8;

  const int tid = threadIdx.x;
  const int lane = tid & 63;
  const int wid = tid >> 6;          // wave = 64-col band
  const int fr = lane & 15;
  const int fg = lane >> 4;

  // staging: A 2 loads, B 4 loads per thread per slice (inverse-swizzled src)
  const unsigned short* aSrc[2]; int aDst[2];
  #pragma unroll
  for (int l = 0; l < 2; l++){
    const int s = l * 256 + tid;
    const int r = s >> 2, c = s & 3;
    aSrc[l] = A + (size_t)(m0 + r) * K + ((c ^ ((r >> 1) & 3)) << 3);
    aDst[l] = s * 16;
  }
  const unsigned short* bSrc[4]; int bDst[4];
  #pragma unroll
  for (int l = 0; l < 4; l++){
    const int s = l * 256 + tid;
    const int r = s >> 2, c = s & 3;
    bSrc[l] = BT + (size_t)(n0 + r) * K + ((c ^ ((r >> 1) & 3)) << 3);
    bDst[l] = 8192 + s * 16;
  }

  // fragment read offsets (slice-relative, swizzled)
  int aOff[8], bOff[4];
  #pragma unroll
  for (int mi = 0; mi < 8; mi++){
    const int row = mi * 16 + fr;
    aOff[mi] = row * 64 + ((fg ^ ((row >> 1) & 3)) << 4);
  }
  #pragma unroll
  for (int nj = 0; nj < 4; nj++){
    const int row = wid * 64 + nj * 16 + fr;
    bOff[nj] = 8192 + row * 64 + ((fg ^ ((row >> 1) & 3)) << 4);
  }

  f32x4 acc[8][4];
  #pragma unroll
  for (int i = 0; i < 8; i++)
    #pragma unroll
    for (int j = 0; j < 4; j++) acc[i][j] = (f32x4){0.f, 0.f, 0.f, 0.f};

#define STAGE5(sl, slot) do { \
    gload_lds16(aSrc[0] + (size_t)(sl) * 32, lds + (slot) + aDst[0]); \
    gload_lds16(aSrc[1] + (size_t)(sl) * 32, lds + (slot) + aDst[1]); \
    gload_lds16(bSrc[0] + (size_t)(sl) * 32, lds + (slot) + bDst[0]); \
    gload_lds16(bSrc[1] + (size_t)(sl) * 32, lds + (slot) + bDst[1]); \
    gload_lds16(bSrc[2] + (size_t)(sl) * 32, lds + (slot) + bDst[2]); \
    gload_lds16(bSrc[3] + (size_t)(sl) * 32, lds + (slot) + bDst[3]); \
  } while (0)

  const int NS = K >> 5;

  STAGE5(0, 0);
  STAGE5(1, SLOT);
  asm volatile("s_waitcnt vmcnt(6)" ::: "memory");
  __builtin_amdgcn_s_barrier();
  asm volatile("" ::: "memory");

  int cs = 0, cg = 2 * SLOT;
  for (int s = 0; s < NS; s++){
    // frags for slice s
    short8 aF[8], bF[4];
    #pragma unroll
    for (int mi = 0; mi < 8; mi++)
      aF[mi] = *(const short8*)(lds + cs + aOff[mi]);
    #pragma unroll
    for (int nj = 0; nj < 4; nj++)
      bF[nj] = *(const short8*)(lds + cs + bOff[nj]);
    // stage slice s+2
    if (s + 2 < NS) STAGE5(s + 2, cg);
    // 32 MFMA, compiler-interleaved with the ds_reads (counted lgkm waits)
    #pragma unroll
    for (int mi = 0; mi < 8; mi++)
      #pragma unroll
      for (int nj = 0; nj < 4; nj++)
        acc[mi][nj] = mfma_bf16(aF[mi], bF[nj], acc[mi][nj]);

    if (s + 2 < NS){
      asm volatile("s_waitcnt vmcnt(6)" ::: "memory");
    } else if (s + 1 < NS){
      asm volatile("s_waitcnt vmcnt(0)" ::: "memory");
    }
    __builtin_amdgcn_s_barrier();
    asm volatile("" ::: "memory");

    cs += SLOT; if (cs == 3 * SLOT) cs = 0;
    cg += SLOT; if (cg == 3 * SLOT) cg = 0;
  }
#undef STAGE5

  // epilogue
  #pragma unroll
  for (int mi = 0; mi < 8; mi++){
    const int mrow = m0 + mi * 16 + fg * 4;
    #pragma unroll
    for (int nj = 0; nj < 4; nj++){
      const int ncol = n0 + wid * 64 + nj * 16 + fr;
      const float bv = bias[ncol];
      #pragma unroll
      for (int r2 = 0; r2 < 4; r2++){
        const size_t idx = (size_t)(mrow + r2) * N + ncol;
        float v = acc[mi][nj][r2] + bv;
        if (EPI == EPI_RESF32){
          ((float*)outp)[idx] = v + res[idx];
        } else if (EPI == EPI_GELU){
          ((unsigned short*)outp)[idx] = f2bf(gelu_fast(v));
        } else {
          ((unsigned short*)outp)[idx] = f2bf(v);
        }
      }
    }
  }
}

// ===== GEMM v5 (gemm4, kept for N=1024 shapes: proj, fc2) ==================
template<int EPI, int BN>
__global__ __launch_bounds__(512, 2) void gemm4_kernel(
    const unsigned short* __restrict__ A,
    const unsigned short* __restrict__ BT,
    const float* __restrict__ bias,
    const float* __restrict__ res,
    void* __restrict__ outp,
    int M, int N, int K)
{
  constexpr int MI   = (BN == 256) ? 8 : 4;
  constexpr int SP   = MI / 4;
  constexpr int NBL  = BN / 128;
  constexpr int WN   = (BN == 256) ? 4 : 2;
  constexpr int WROWS= (BN == 256) ? 128 : 64;
  constexpr int ASL  = 16384;
  constexpr int SLOT = ASL + BN * 64;
  __shared__ __align__(16) char lds[4 * SLOT];

  const int nwg = gridDim.x;
  const int bid = blockIdx.x;
  const int wg = (bid & 7) * (nwg >> 3) + (bid >> 3);
  const int NTile = N / BN;
  const int mt = wg / NTile;
  const int nti = wg - mt * NTile;
  const int m0 = mt << 8;
  const int n0 = nti * BN;

  const int tid = threadIdx.x;
  const int lane = tid & 63;
  const int wid = tid >> 6;
  const int wv_m = wid / WN;
  const int wv_n = wid % WN;
  const int fr = lane & 15;
  const int fg = lane >> 4;

  const unsigned short* aSrc[2];
  int aDst[2];
  #pragma unroll
  for (int l = 0; l < 2; l++){
    const int s = l * 512 + tid;
    const int r = s >> 2, c = s & 3;
    aSrc[l] = A + (size_t)(m0 + r) * K + ((c ^ ((r >> 1) & 3)) << 3);
    aDst[l] = s * 16;
  }
  const unsigned short* bSrc[NBL];
  int bDst[NBL];
  #pragma unroll
  for (int l = 0; l < NBL; l++){
    const int s = l * 512 + tid;
    const int r = s >> 2, c = s & 3;
    bSrc[l] = BT + (size_t)(n0 + r) * K + ((c ^ ((r >> 1) & 3)) << 3);
    bDst[l] = ASL + s * 16;
  }

  int aOff[MI], bOff[4];
  #pragma unroll
  for (int mi = 0; mi < MI; mi++){
    const int row = wv_m * WROWS + mi * 16 + fr;
    aOff[mi] = row * 64 + ((fg ^ ((row >> 1) & 3)) << 4);
  }
  #pragma unroll
  for (int nj = 0; nj < 4; nj++){
    const int row = wv_n * 64 + nj * 16 + fr;
    bOff[nj] = ASL + row * 64 + ((fg ^ ((row >> 1) & 3)) << 4);
  }

  f32x4 acc[MI][4];
  #pragma unroll
  for (int i = 0; i < MI; i++)
    #pragma unroll
    for (int j = 0; j < 4; j++) acc[i][j] = (f32x4){0.f, 0.f, 0.f, 0.f};

#define STAGE_A(sl, slot) do { \
    gload_lds16(aSrc[0] + (size_t)(sl) * 32, lds + (slot) + aDst[0]); \
    gload_lds16(aSrc[1] + (size_t)(sl) * 32, lds + (slot) + aDst[1]); \
  } while (0)
#define STAGE_B(sl, slot) do { \
    gload_lds16(bSrc[0] + (size_t)(sl) * 32, lds + (slot) + bDst[0]); \
    if (NBL == 2) gload_lds16(bSrc[1] + (size_t)(sl) * 32, lds + (slot) + bDst[1]); \
  } while (0)

  const int NS = K >> 5;

  STAGE_A(0, 0);        STAGE_B(0, 0);
  STAGE_A(1, SLOT);     STAGE_B(1, SLOT);
  STAGE_A(2, 2 * SLOT); STAGE_B(2, 2 * SLOT);
  if (BN == 256) asm volatile("s_waitcnt vmcnt(8)" ::: "memory");
  else           asm volatile("s_waitcnt vmcnt(6)" ::: "memory");
  __builtin_amdgcn_s_barrier();

  for (int s = 0; s < NS; s++){
    const int ss = (s & 3) * SLOT;
    const int sg = ((s + 3) & 3) * SLOT;
    const bool pf = (s + 3 < NS);
    short8 bF[4];
    #pragma unroll
    for (int sp = 0; sp < SP; sp++){
      short8 aF[4];
      #pragma unroll
      for (int i = 0; i < 4; i++)
        aF[i] = *(const short8*)(lds + ss + aOff[sp * 4 + i]);
      if (sp == 0){
        #pragma unroll
        for (int nj = 0; nj < 4; nj++)
          bF[nj] = *(const short8*)(lds + ss + bOff[nj]);
      }
      if (pf){
        if (SP == 2){
          if (sp == 0) STAGE_A(s + 3, sg);
          else         STAGE_B(s + 3, sg);
        } else {
          STAGE_A(s + 3, sg);
          STAGE_B(s + 3, sg);
        }
      }
      __builtin_amdgcn_s_barrier();
      asm volatile("s_waitcnt lgkmcnt(0)" ::: "memory");
      __builtin_amdgcn_sched_barrier(0);
      __builtin_amdgcn_s_setprio(1);
      #pragma unroll
      for (int i = 0; i < 4; i++)
        #pragma unroll
        for (int nj = 0; nj < 4; nj++)
          acc[sp * 4 + i][nj] = mfma_bf16(aF[i], bF[nj], acc[sp * 4 + i][nj]);
      __builtin_amdgcn_s_setprio(0);
      if (sp == SP - 1){
        if (s + 3 < NS){
          if (BN == 256) asm volatile("s_waitcnt vmcnt(8)" ::: "memory");
          else           asm volatile("s_waitcnt vmcnt(6)" ::: "memory");
        } else if (s + 2 < NS){
          if (BN == 256) asm volatile("s_waitcnt vmcnt(4)" ::: "memory");
          else           asm volatile("s_waitcnt vmcnt(3)" ::: "memory");
        } else if (s + 1 < NS){
          asm volatile("s_waitcnt vmcnt(0)" ::: "memory");
        }
      }
      __builtin_amdgcn_s_barrier();
    }
  }
#undef STAGE_A
#undef STAGE_B

  #pragma unroll
  for (int mi = 0; mi < MI; mi++){
    const int mrow = m0 + wv_m * WROWS + mi * 16 + fg * 4;
    #pragma unroll
    for (int nj = 0; nj < 4; nj++){
      const int ncol = n0 + wv_n * 64 + nj * 16 + fr;
      const float bv = bias[ncol];
      #pragma unroll
      for (int r2 = 0; r2 < 4; r2++){
        const size_t idx = (size_t)(mrow + r2) * N + ncol;
        float v = acc[mi][nj][r2] + bv;
        if (EPI == EPI_RESF32){
          ((float*)outp)[idx] = v + res[idx];
        } else if (EPI == EPI_GELU){
          ((unsigned short*)outp)[idx] = f2bf(gelu_fast(v));
        } else {
          ((unsigned short*)outp)[idx] = f2bf(v);
        }
      }
    }
  }
}

// ===== causal flash attention (unchanged) =====
template<bool MASK>
__device__ __forceinline__ void attn_tile(
    const unsigned short* __restrict__ Kc, const unsigned short* __restrict__ Vc,
    const short8 (&qf)[4], int kvbase, int qg, int l31, int hi,
    float& m_r, float& lsum, f32x16& Oa, f32x16& Ob)
{
  f32x16 Sa = zero16();
  f32x16 Sb = zero16();
  const int xb = l31 & 7;
  #pragma unroll
  for (int kk = 0; kk < 4; kk++){
    const int x = kk * 2 + hi;
    const short8 k0 = *(const short8*)((const char*)Kc + l31 * 128 + ((x ^ xb) << 4));
    const short8 k1 = *(const short8*)((const char*)Kc + (l31 + 32) * 128 + ((x ^ xb) << 4));
    Sa = mfma32(k0, qf[kk], Sa);
    Sb = mfma32(k1, qf[kk], Sb);
  }
  if (MASK){
    #pragma unroll
    for (int r = 0; r < 16; r++){
      const int kva = kvbase + (r & 3) + 8 * (r >> 2) + 4 * hi;
      Sa[r] = (kva > qg)      ? -1e30f : Sa[r];
      Sb[r] = (kva + 32 > qg) ? -1e30f : Sb[r];
    }
  }
  float tmax = Sa[0];
  #pragma unroll
  for (int r = 1; r < 16; r++) tmax = fmaxf(tmax, Sa[r]);
  #pragma unroll
  for (int r = 0; r < 16; r++) tmax = fmaxf(tmax, Sb[r]);
  tmax = fmaxf(tmax, __shfl_xor(tmax, 32));
  if (__any(tmax > m_r + 10.0f)){
    const float mn = fmaxf(m_r, tmax);
    const float sc = exp2g(m_r - mn);
    m_r = mn;
    lsum *= sc;
    #pragma unroll
    for (int r = 0; r < 16; r++){ Oa[r] *= sc; Ob[r] *= sc; }
  }
  float rs = 0.0f;
  #pragma unroll
  for (int r = 0; r < 16; r++){
    Sa[r] = exp2g(Sa[r] - m_r); rs += Sa[r];
    Sb[r] = exp2g(Sb[r] - m_r); rs += Sb[r];
  }
  rs += __shfl_xor(rs, 32);
  lsum += rs;

  short8 pf[4];
  {
    uint32 a0 = cvtpk_bf(Sa[0], Sa[1]),   b0 = cvtpk_bf(Sa[4], Sa[5]);
    uint32 a1 = cvtpk_bf(Sa[2], Sa[3]),   b1 = cvtpk_bf(Sa[6], Sa[7]);
    plswap(a0, b0); plswap(a1, b1);
    uint32 a2 = cvtpk_bf(Sa[8], Sa[9]),   b2 = cvtpk_bf(Sa[12], Sa[13]);
    uint32 a3 = cvtpk_bf(Sa[10], Sa[11]), b3 = cvtpk_bf(Sa[14], Sa[15]);
    plswap(a2, b2); plswap(a3, b3);
    union { uint32 u[4]; short8 s; } m0, m1;
    m0.u[0] = a0; m0.u[1] = a1; m0.u[2] = b0; m0.u[3] = b1;
    m1.u[0] = a2; m1.u[1] = a3; m1.u[2] = b2; m1.u[3] = b3;
    pf[0] = m0.s; pf[1] = m1.s;
  }
  {
    uint32 a0 = cvtpk_bf(Sb[0], Sb[1]),   b0 = cvtpk_bf(Sb[4], Sb[5]);
    uint32 a1 = cvtpk_bf(Sb[2], Sb[3]),   b1 = cvtpk_bf(Sb[6], Sb[7]);
    plswap(a0, b0); plswap(a1, b1);
    uint32 a2 = cvtpk_bf(Sb[8], Sb[9]),   b2 = cvtpk_bf(Sb[12], Sb[13]);
    uint32 a3 = cvtpk_bf(Sb[10], Sb[11]), b3 = cvtpk_bf(Sb[14], Sb[15]);
    plswap(a2, b2); plswap(a3, b3);
    union { uint32 u[4]; short8 s; } m0, m1;
    m0.u[0] = a0; m0.u[1] = a1; m0.u[2] = b0; m0.u[3] = b1;
    m1.u[0] = a2; m1.u[1] = a3; m1.u[2] = b2; m1.u[3] = b3;
    pf[2] = m0.s; pf[3] = m1.s;
  }
  #pragma unroll
  for (int kk = 0; kk < 4; kk++){
    const int x = kk * 2 + hi;
    const short8 v0 = *(const short8*)((const char*)Vc + l31 * 128 + ((x ^ xb) << 4));
    const short8 v1 = *(const short8*)((const char*)Vc + (l31 + 32) * 128 + ((x ^ xb) << 4));
    Oa = mfma32(v0, pf[kk], Oa);
    Ob = mfma32(v1, pf[kk], Ob);
  }
}

__global__ __launch_bounds__(256) void attn_kernel(
    const unsigned short* __restrict__ qkv,
    const unsigned short* __restrict__ vt,
    unsigned short* __restrict__ y)
{
  __shared__ __align__(16) unsigned short Klds[2][4096];
  __shared__ __align__(16) unsigned short Vlds[2][4096];
  const int bid = blockIdx.x;
  const int bh = bid & 63;
  const int qb_i = bid >> 6;
  const int b = bh >> 4, h = bh & 15;
  const int qb0 = qb_i * 128;
  const int tid = threadIdx.x;
  const int w = tid >> 6;
  const int lane = tid & 63;
  const int l31 = lane & 31;
  const int hi = lane >> 5;

  const int qrow_g = b * 2048 + qb0 + w * 32 + l31;
  const unsigned short* qp = qkv + (size_t)qrow_g * 3072 + h * 64;
  short8 qf[4];
  #pragma unroll
  for (int kk = 0; kk < 4; kk++){
    short8 raw = *(const short8*)&qp[kk * 16 + hi * 8];
    #pragma unroll
    for (int j = 0; j < 8; j++)
      qf[kk][j] = (short)f2bf(bf2f((unsigned short)raw[j]) * 0.18033688011112042f);
  }

  const int sr = tid >> 3;
  const int ce = ((tid & 7) ^ (sr & 7)) * 8;
  const unsigned short* kb = qkv + (size_t)(b * 2048) * 3072 + 1024 + h * 64;
  const unsigned short* vb = vt + (size_t)bh * 64 * 2048;

  f32x16 Oa = zero16(), Ob = zero16();
  float m_r = -1e30f, lsum = 0.0f;
  const int qmin = qb0 + w * 32;
  const int qmax = qmin + 31;
  const int qg = qmin + l31;
  const int nkv = (qb0 >> 6) + 2;

#define STAGE(t, bb) do { \
    const size_t kro = (size_t)((t) * 64 + sr) * 3072; \
    gload_lds16(kb + kro + ce,                         (char*)&Klds[bb][0] + tid * 16); \
    gload_lds16(kb + kro + (size_t)32 * 3072 + ce,     (char*)&Klds[bb][0] + 4096 + tid * 16); \
    gload_lds16(vb + (size_t)sr * 2048 + (t) * 64 + ce,        (char*)&Vlds[bb][0] + tid * 16); \
    gload_lds16(vb + (size_t)(sr + 32) * 2048 + (t) * 64 + ce, (char*)&Vlds[bb][0] + 4096 + tid * 16); \
  } while (0)

  STAGE(0, 0);
  __syncthreads();
  int cur = 0;
  for (int kvt = 0; kvt < nkv; kvt++){
    if (kvt + 1 < nkv){
      if (cur) STAGE(kvt + 1, 0); else STAGE(kvt + 1, 1);
    }
    if (kvt * 64 <= qmax){
      if (kvt * 64 + 63 <= qmin)
        attn_tile<false>(Klds[cur], Vlds[cur], qf, kvt * 64, qg, l31, hi, m_r, lsum, Oa, Ob);
      else
        attn_tile<true >(Klds[cur], Vlds[cur], qf, kvt * 64, qg, l31, hi, m_r, lsum, Oa, Ob);
    }
    __syncthreads();
    cur ^= 1;
  }
#undef STAGE

  const float inv = 1.0f / lsum;
  unsigned short* yp = y + (size_t)qrow_g * 1024 + h * 64;
  #pragma unroll
  for (int c2 = 0; c2 < 4; c2++){
    uint2v da, db;
    da.x = cvtpk_bf(Oa[4 * c2 + 0] * inv, Oa[4 * c2 + 1] * inv);
    da.y = cvtpk_bf(Oa[4 * c2 + 2] * inv, Oa[4 * c2 + 3] * inv);
    *(uint2v*)&yp[8 * c2 + 4 * hi] = da;
    db.x = cvtpk_bf(Ob[4 * c2 + 0] * inv, Ob[4 * c2 + 1] * inv);
    db.y = cvtpk_bf(Ob[4 * c2 + 2] * inv, Ob[4 * c2 + 3] * inv);
    *(uint2v*)&yp[32 + 8 * c2 + 4 * hi] = db;
  }
}

// ===== launch =====
extern "C" void kernel_launch(void* const* d_in, const int* in_sizes, int n_in,
                              void* d_out, int out_size, void* d_ws, size_t ws_size,
                              hipStream_t stream)
{
  const float* x      = (const float*)d_in[0];
  const float* ln1_w  = (const float*)d_in[1];
  const float* ln1_b  = (const float*)d_in[2];
  const float* w_attn = (const float*)d_in[3];
  const float* b_attn = (const float*)d_in[4];
  const float* w_proj = (const float*)d_in[5];
  const float* b_proj = (const float*)d_in[6];
  const float* ln2_w  = (const float*)d_in[7];
  const float* ln2_b  = (const float*)d_in[8];
  const float* w_fc   = (const float*)d_in[9];
  const float* b_fc   = (const float*)d_in[10];
  const float* w_fc2  = (const float*)d_in[11];
  const float* b_fc2  = (const float*)d_in[12];

  char* ws = (char*)d_ws;
  unsigned short* wbT_attn = (unsigned short*)(ws + 0);          //  [3072][1024]
  unsigned short* wbT_proj = (unsigned short*)(ws + 6291456);    //  [1024][1024]
  unsigned short* wbT_fc   = (unsigned short*)(ws + 8388608);    //  [4096][1024]
  unsigned short* wbT_fc2  = (unsigned short*)(ws + 16777216);   //  [1024][4096]
  unsigned short* h_bf     = (unsigned short*)(ws + 25165824);   //  [8192][1024]
  unsigned short* qkv_bf   = (unsigned short*)(ws + 41943040);   //  [8192][3072]
  unsigned short* vt_bf    = (unsigned short*)(ws + 92274688);   //  [64][64][2048]
  unsigned short* g_bf     = (unsigned short*)(ws + 41943040);   //  alias qkv+vt: [8192][4096]
  unsigned short* y_bf     = (unsigned short*)(ws + 109051904);  //  [8192][1024]
  float*          x1       = (float*)(ws + 125829120);           //  [8192][1024]
  float* outf = (float*)d_out;

  wtrans_kernel<<<dim3(3072/32, 1024/32), 256, 0, stream>>>(w_attn, wbT_attn, 1024, 3072);
  wtrans_kernel<<<dim3(1024/32, 1024/32), 256, 0, stream>>>(w_proj, wbT_proj, 1024, 1024);
  wtrans_kernel<<<dim3(4096/32, 1024/32), 256, 0, stream>>>(w_fc,   wbT_fc,   1024, 4096);
  wtrans_kernel<<<dim3(1024/32, 4096/32), 256, 0, stream>>>(w_fc2,  wbT_fc2,  4096, 1024);

  // LN1: x -> h_bf
  ln_kernel<<<8192, 256, 0, stream>>>(x, ln1_w, ln1_b, h_bf);
  // qkv = h @ w_attn + b_attn   (grid = 64 m x 12 n = 768, 2 blocks/CU)
  gemm5_kernel<EPI_BF16><<<768, 256, 0, stream>>>(
      h_bf, wbT_attn, b_attn, nullptr, qkv_bf, 8192, 3072, 1024);
  // V transpose for PV operand
  vtrans_kernel<<<dim3(64, 2, 64), 256, 0, stream>>>(qkv_bf, vt_bf);
  // causal flash attention -> y_bf
  attn_kernel<<<1024, 256, 0, stream>>>(qkv_bf, vt_bf, y_bf);
  // x1 = x + y @ w_proj + b_proj   (grid = 32 x 8 = 256)
  gemm4_kernel<EPI_RESF32, 128><<<256, 512, 0, stream>>>(
      y_bf, wbT_proj, b_proj, x, x1, 8192, 1024, 1024);
  // LN2: x1 -> h_bf
  ln_kernel<<<8192, 256, 0, stream>>>(x1, ln2_w, ln2_b, h_bf);
  // g = gelu(h2 @ w_fc + b_fc)   (grid = 64 m x 16 n = 1024, 2 blocks/CU)
  gemm5_kernel<EPI_GELU><<<1024, 256, 0, stream>>>(
      h_bf, wbT_fc, b_fc, nullptr, g_bf, 8192, 4096, 1024);
  // out = x1 + g @ w_fc2 + b_fc2   (grid = 32 x 8 = 256)
  gemm4_kernel<EPI_RESF32, 128><<<256, 512, 0, stream>>>(
      g_bf, wbT_fc2, b_fc2, x1, outf, 8192, 1024, 4096);
}